// Round 1
// baseline (843.675 us; speedup 1.0000x reference)
//
#include <hip/hip_runtime.h>

// GIN 2-layer forward, MI355X (gfx950). Round 12:
//  - col-blocked gather: CSR adjacency ordered by (node, col-block) with 4
//    col-blocks of 12500 nodes (3.2MB bf16 rows = fits one XCD's 4MB L2).
//  - persistent gather kernel: 1024 blocks (exactly co-resident at
//    __launch_bounds__(256,4)), 13 nodes/wave, fp32 accumulators in regs,
//    device-wide pass sweep block0->1->2->3 with deadlock-free soft
//    barriers (bounded s_sleep spin; correctness never depends on them).
//  - agg writes nontemporal (don't evict the resident col-block).
//  - CSR build: binB extended to count per (node, col-block), emit suboffs.
//  - everything else identical to round 11.

#define N_NODES 50000
#define N_EDGES 800000
#define DIM 128
#define BN_EPS 1e-5f
#define NB 196                  // ceil(N_NODES/256) scan blocks
#define GEMM_GRID 782           // ceil(N_NODES/64)
#define NBUCK 256
#define NPB 196                 // nodes per bucket
#define BCAP 4096               // max edges per bucket
#define BINA_BLOCKS 128
#define EPB (N_EDGES / BINA_BLOCKS)
#define CBLK 12500              // col-block width (4 blocks, 3.2MB bf16 each)
#define GW_BLOCKS 1024          // persistent gather grid (4 blocks/CU)
#define NPW 13                  // nodes per wave: 1024*4*13 = 53248 >= 50000

using bfrag8 = __attribute__((ext_vector_type(8))) short;
using accf4  = __attribute__((ext_vector_type(4))) float;

__device__ __forceinline__ float bf2f(unsigned short u) {
  union { unsigned u32; float f; } c;
  c.u32 = ((unsigned)u) << 16;
  return c.f;
}
__device__ __forceinline__ unsigned short f2bf(float f) {
  union { float f; unsigned u32; } c;
  c.f = f;
  unsigned u = c.u32;
  return (unsigned short)((u + 0x7fffu + ((u >> 16) & 1u)) >> 16);  // RNE
}

// ---- dtype detector ----
__global__ void detect_kernel(const unsigned short* __restrict__ xs,
                              int* __restrict__ flag) {
  __shared__ int oks[64];
  int t = threadIdx.x;
  unsigned short u = xs[t * 2];
  int e = (u >> 7) & 0xFF;
  oks[t] = ((e >= 96 && e <= 134) || ((u & 0x7FFFu) == 0)) ? 1 : 0;
  __syncthreads();
  if (t == 0) {
    int c = 0;
    for (int i = 0; i < 64; ++i) c += oks[i];
    *flag = (c >= 56) ? 1 : 0;  // 1 = bf16, 0 = fp32
  }
}

// ---- prep: pack weights into MFMA B-frag layout + convert vectors ----
struct PPtrs { const void* w[4]; const void* v[10]; };

__global__ __launch_bounds__(256) void prep_kernel(
    PPtrs pp, unsigned short* __restrict__ PW, float* __restrict__ PV,
    const int* __restrict__ flagp) {
  int bf = *flagp;
  if (blockIdx.x < 4) {
    int mat = blockIdx.x;
    const void* src = pp.w[mat];
    unsigned short* dst = PW + (size_t)mat * 16384;
    for (int f = threadIdx.x; f < 2048; f += 256) {
      int kt = f >> 9, nt = (f >> 6) & 7, lane = f & 63;
      int kbase = kt * 32 + (lane >> 4) * 8;
      int n = nt * 16 + (lane & 15);
      unsigned short tmp[8];
      for (int j = 0; j < 8; ++j) {
        int idx = (kbase + j) * DIM + n;
        if (bf) tmp[j] = ((const unsigned short*)src)[idx];
        else    tmp[j] = f2bf(((const float*)src)[idx]);
      }
      for (int j = 0; j < 8; ++j) dst[f * 8 + j] = tmp[j];
    }
  } else {
    for (int j = threadIdx.x; j < 10 * DIM; j += 256) {
      int vec = j >> 7, idx = j & 127;
      float v;
      if (bf) v = bf2f(((const unsigned short*)pp.v[vec])[idx]);
      else    v = ((const float*)pp.v[vec])[idx];
      PV[j] = v;
    }
  }
}

// ================= CSR build =================
__global__ __launch_bounds__(256) void binA_kernel(
    const int* __restrict__ row, const int* __restrict__ col,
    int* __restrict__ deg, int* __restrict__ bcnt, uint2* __restrict__ ebuf) {
  __shared__ int hist[NBUCK];
  __shared__ int base[NBUCK];
  int t = threadIdx.x;
  int e0 = blockIdx.x * EPB;
  hist[t] = 0;
  __syncthreads();
  for (int i = t; i < EPB; i += 256) {
    int r = row[e0 + i];
    atomicAdd(&deg[r], 1);
    atomicAdd(&hist[r / NPB], 1);
  }
  __syncthreads();
  base[t] = atomicAdd(&bcnt[t], hist[t]);
  hist[t] = 0;
  __syncthreads();
  for (int i = t; i < EPB; i += 256) {
    int r = row[e0 + i];
    int c = col[e0 + i];
    int b = r / NPB;
    int rank = atomicAdd(&hist[b], 1);
    ebuf[(size_t)b * BCAP + base[b] + rank] = make_uint2((unsigned)r, (unsigned)c);
  }
}

__global__ __launch_bounds__(256) void bsum_kernel(
    const int* __restrict__ deg, int* __restrict__ bsum) {
  __shared__ int s[256];
  int i = blockIdx.x * 256 + threadIdx.x;
  s[threadIdx.x] = (i < N_NODES) ? deg[i] : 0;
  __syncthreads();
  for (int d = 128; d > 0; d >>= 1) {
    if (threadIdx.x < d) s[threadIdx.x] += s[threadIdx.x + d];
    __syncthreads();
  }
  if (threadIdx.x == 0) bsum[blockIdx.x] = s[0];
}

__global__ __launch_bounds__(256) void bscan_kernel(
    const int* __restrict__ bsum, int* __restrict__ bscan) {
  __shared__ int s[256];
  int t = threadIdx.x;
  int v = (t < NB) ? bsum[t] : 0;
  s[t] = v;
  __syncthreads();
  for (int d = 1; d < 256; d <<= 1) {
    int tv = (t >= d) ? s[t - d] : 0;
    __syncthreads();
    s[t] += tv;
    __syncthreads();
  }
  if (t < NB) bscan[t] = s[t] - v;  // exclusive
}

__global__ __launch_bounds__(256) void offs_kernel(
    const int* __restrict__ deg, const int* __restrict__ bscan,
    int* __restrict__ offs) {
  __shared__ int s[256];
  int t = threadIdx.x;
  int i = blockIdx.x * 256 + t;
  int v = (i < N_NODES) ? deg[i] : 0;
  s[t] = v;
  __syncthreads();
  for (int d = 1; d < 256; d <<= 1) {
    int tv = (t >= d) ? s[t - d] : 0;
    __syncthreads();
    s[t] += tv;
    __syncthreads();
  }
  if (i < N_NODES) {
    int excl = bscan[blockIdx.x] + s[t] - v;
    offs[i] = excl;
    if (i == N_NODES - 1) offs[N_NODES] = excl + v;
  }
}

// binB: order each node's neighbor list by col-block, emit per-node
// sub-offsets suboffs[node][blk] (absolute positions in csr_col).
__global__ __launch_bounds__(256) void binB_kernel(
    const int* __restrict__ offs, const int* __restrict__ bcnt,
    const uint2* __restrict__ ebuf, int* __restrict__ csr_col,
    int* __restrict__ suboffs) {
  __shared__ int cur4[NPB * 4];
  __shared__ int seg[BCAP];
  int b = blockIdx.x;
  int nb = b * NPB;
  int nend = nb + NPB;
  if (nend > N_NODES) nend = N_NODES;
  int nn = nend - nb;
  int segbase = offs[nb];
  int seglen = offs[nend] - segbase;
  int cnt = bcnt[b];
  const uint2* eb = ebuf + (size_t)b * BCAP;
  for (int i = threadIdx.x; i < nn * 4; i += 256) cur4[i] = 0;
  __syncthreads();
  // count per (node, col-block)
  for (int i = threadIdx.x; i < cnt; i += 256) {
    uint2 e = eb[i];
    int blk = (int)e.y / CBLK;
    atomicAdd(&cur4[(e.x - (unsigned)nb) * 4 + blk], 1);
  }
  __syncthreads();
  // per-node 4-way prefix -> local running starts + global suboffs
  for (int t = threadIdx.x; t < nn; t += 256) {
    int base0 = offs[nb + t];
    int run = base0 - segbase;
    int c0 = cur4[t * 4 + 0], c1 = cur4[t * 4 + 1];
    int c2 = cur4[t * 4 + 2];
    cur4[t * 4 + 0] = run;
    cur4[t * 4 + 1] = run + c0;
    cur4[t * 4 + 2] = run + c0 + c1;
    cur4[t * 4 + 3] = run + c0 + c1 + c2;
    suboffs[(nb + t) * 4 + 0] = base0;
    suboffs[(nb + t) * 4 + 1] = base0 + c0;
    suboffs[(nb + t) * 4 + 2] = base0 + c0 + c1;
    suboffs[(nb + t) * 4 + 3] = base0 + c0 + c1 + c2;
  }
  __syncthreads();
  // scatter in (node, blk) order
  for (int i = threadIdx.x; i < cnt; i += 256) {
    uint2 e = eb[i];
    int blk = (int)e.y / CBLK;
    int slot = atomicAdd(&cur4[(e.x - (unsigned)nb) * 4 + blk], 1);
    seg[slot] = (int)e.y;
  }
  __syncthreads();
  for (int i = threadIdx.x; i < seglen; i += 256)
    csr_col[segbase + i] = seg[i];
}

// ---- deadlock-free soft device barrier (perf-only, bounded spin) ----
__device__ __forceinline__ void soft_barrier(int* ctr, int target) {
  __syncthreads();
  if (threadIdx.x == 0) {
    atomicAdd(ctr, 1);
    for (int it = 0; it < 64; ++it) {
      if (__hip_atomic_load(ctr, __ATOMIC_RELAXED, __HIP_MEMORY_SCOPE_AGENT) >=
          target)
        break;
      __builtin_amdgcn_s_sleep(16);
    }
  }
  __syncthreads();
}

// ================= persistent col-blocked gather =================
// Wave = 13 nodes, lane owns 2 channels. Whole device sweeps the 4
// col-blocks in lockstep (soft barriers) so each pass's 3.2MB source
// block stays resident in every XCD's 4MB L2.
// mode 0: plain sum (src dtype per flag); mode 1: relu(v*sc+sh), bf16 src.
__global__ __launch_bounds__(256, 4) void gather_pass_kernel(
    const void* __restrict__ src, const int* __restrict__ offs,
    const int* __restrict__ suboffs, const int* __restrict__ csr_col,
    const float* __restrict__ ss, unsigned short* __restrict__ agg,
    const int* __restrict__ flagp, int* __restrict__ pcnt, int mode) {
  const int wid = blockIdx.x * 4 + (threadIdx.x >> 6);
  const int lane = threadIdx.x & 63;
  const int ch = lane * 2;
  const int nbase = wid * NPW;
  const int bf = *flagp;
  const bool is_bf = (mode == 1) || bf;
  float sc0 = 0.f, sc1 = 0.f, sh0 = 0.f, sh1 = 0.f;
  if (mode == 1) {
    sc0 = ss[ch]; sc1 = ss[ch + 1];
    sh0 = ss[DIM + ch]; sh1 = ss[DIM + ch + 1];
  }
  float a0[NPW], a1[NPW];
#pragma unroll
  for (int p = 0; p < NPW; ++p) { a0[p] = 0.f; a1[p] = 0.f; }
  const unsigned short* h = (const unsigned short*)src;
  const float* xf = (const float*)src;

  for (int b = 0; b < 4; ++b) {
#pragma unroll
    for (int p = 0; p < NPW; ++p) {
      int node = nbase + p;
      if (node >= N_NODES) break;
      int j = suboffs[node * 4 + b];
      int jend = (b == 3) ? offs[node + 1] : suboffs[node * 4 + b + 1];
      float s0 = a0[p], s1 = a1[p];
      if (is_bf) {
        for (; j + 3 < jend; j += 4) {
          int ix0 = csr_col[j], ix1 = csr_col[j + 1];
          int ix2 = csr_col[j + 2], ix3 = csr_col[j + 3];
          unsigned u0 = *(const unsigned*)(h + (size_t)ix0 * DIM + ch);
          unsigned u1 = *(const unsigned*)(h + (size_t)ix1 * DIM + ch);
          unsigned u2 = *(const unsigned*)(h + (size_t)ix2 * DIM + ch);
          unsigned u3 = *(const unsigned*)(h + (size_t)ix3 * DIM + ch);
          if (mode == 1) {
            s0 += fmaxf(bf2f((unsigned short)u0) * sc0 + sh0, 0.f);
            s1 += fmaxf(bf2f((unsigned short)(u0 >> 16)) * sc1 + sh1, 0.f);
            s0 += fmaxf(bf2f((unsigned short)u1) * sc0 + sh0, 0.f);
            s1 += fmaxf(bf2f((unsigned short)(u1 >> 16)) * sc1 + sh1, 0.f);
            s0 += fmaxf(bf2f((unsigned short)u2) * sc0 + sh0, 0.f);
            s1 += fmaxf(bf2f((unsigned short)(u2 >> 16)) * sc1 + sh1, 0.f);
            s0 += fmaxf(bf2f((unsigned short)u3) * sc0 + sh0, 0.f);
            s1 += fmaxf(bf2f((unsigned short)(u3 >> 16)) * sc1 + sh1, 0.f);
          } else {
            s0 += bf2f((unsigned short)u0);
            s1 += bf2f((unsigned short)(u0 >> 16));
            s0 += bf2f((unsigned short)u1);
            s1 += bf2f((unsigned short)(u1 >> 16));
            s0 += bf2f((unsigned short)u2);
            s1 += bf2f((unsigned short)(u2 >> 16));
            s0 += bf2f((unsigned short)u3);
            s1 += bf2f((unsigned short)(u3 >> 16));
          }
        }
        for (; j < jend; ++j) {
          int ix = csr_col[j];
          unsigned u = *(const unsigned*)(h + (size_t)ix * DIM + ch);
          if (mode == 1) {
            s0 += fmaxf(bf2f((unsigned short)u) * sc0 + sh0, 0.f);
            s1 += fmaxf(bf2f((unsigned short)(u >> 16)) * sc1 + sh1, 0.f);
          } else {
            s0 += bf2f((unsigned short)u);
            s1 += bf2f((unsigned short)(u >> 16));
          }
        }
      } else {
        for (; j < jend; ++j) {
          float2 v = *(const float2*)(xf + (size_t)csr_col[j] * DIM + ch);
          s0 += v.x; s1 += v.y;
        }
      }
      a0[p] = s0; a1[p] = s1;
    }
    if (b < 3) soft_barrier(pcnt + b, GW_BLOCKS);
  }

#pragma unroll
  for (int p = 0; p < NPW; ++p) {
    int node = nbase + p;
    if (node >= N_NODES) break;
    unsigned o = (unsigned)f2bf(a0[p]) | ((unsigned)f2bf(a1[p]) << 16);
    __builtin_nontemporal_store(o, (unsigned*)(agg + (size_t)node * DIM + ch));
  }
}

// ---- BN finalize: one block per channel ----
__global__ __launch_bounds__(256) void bn_fin_kernel(
    const float* __restrict__ ps, const float* __restrict__ g,
    const float* __restrict__ be, float* __restrict__ ss) {
  __shared__ float s2[256], q2[256];
  int c = blockIdx.x;
  int t = threadIdx.x;
  float s = 0.f, q = 0.f;
  for (int b = t; b < GEMM_GRID; b += 256) {
    s += ps[b * 256 + c];
    q += ps[b * 256 + 128 + c];
  }
  s2[t] = s; q2[t] = q;
  __syncthreads();
  for (int d = 128; d > 0; d >>= 1) {
    if (t < d) { s2[t] += s2[t + d]; q2[t] += q2[t + d]; }
    __syncthreads();
  }
  if (t == 0) {
    const float invN = 1.0f / (float)N_NODES;
    float m = s2[0] * invN;
    float v = q2[0] * invN - m * m;
    float scale = g[c] * rsqrtf(v + BN_EPS);
    ss[c] = scale;
    ss[DIM + c] = be[c] - m * scale;
  }
}

// ================= MFMA GEMM =================
__global__ __launch_bounds__(256) void gemm_kernel(
    const void* __restrict__ Ap, const unsigned short* __restrict__ agg,
    const unsigned short* __restrict__ PWm, const float* __restrict__ bias,
    const float* __restrict__ ss, void* __restrict__ Cp,
    float* __restrict__ ps, const int* __restrict__ flagp,
    int a_ext, int add_agg, int transform, int out_ext, int do_stats) {
  __shared__ unsigned short As[64 * 136];
  __shared__ float red_s[256];
  __shared__ float red_q[256];
  const int tid = threadIdx.x;
  const int row0 = blockIdx.x * 64;
  const int bf = *flagp;

  for (int i = 0; i < 8; ++i) {
    int G = tid + i * 256;
    int lrow = G >> 5;
    int ch = (G & 31) * 4;
    int grow = row0 + lrow;
    float4 v = make_float4(0.f, 0.f, 0.f, 0.f);
    if (grow < N_NODES) {
      if (a_ext && !bf) {
        v = *(const float4*)((const float*)Ap + (size_t)grow * DIM + ch);
      } else {
        ushort4 u = *(const ushort4*)((const unsigned short*)Ap +
                                      (size_t)grow * DIM + ch);
        v = make_float4(bf2f(u.x), bf2f(u.y), bf2f(u.z), bf2f(u.w));
      }
      if (transform) {
        float4 sc = *(const float4*)(ss + ch);
        float4 sh = *(const float4*)(ss + DIM + ch);
        v.x = fmaxf(v.x * sc.x + sh.x, 0.f);
        v.y = fmaxf(v.y * sc.y + sh.y, 0.f);
        v.z = fmaxf(v.z * sc.z + sh.z, 0.f);
        v.w = fmaxf(v.w * sc.w + sh.w, 0.f);
      }
      if (add_agg) {
        ushort4 au = *(const ushort4*)(agg + (size_t)grow * DIM + ch);
        v.x += bf2f(au.x); v.y += bf2f(au.y);
        v.z += bf2f(au.z); v.w += bf2f(au.w);
      }
    }
    ushort4 o;
    o.x = f2bf(v.x); o.y = f2bf(v.y); o.z = f2bf(v.z); o.w = f2bf(v.w);
    *(ushort4*)&As[lrow * 136 + ch] = o;
  }
  __syncthreads();

  const int wv = tid >> 6, lane = tid & 63;
  const int quad = lane >> 4, lo = lane & 15;
  accf4 acc[8];
#pragma unroll
  for (int nt = 0; nt < 8; ++nt) {
    acc[nt][0] = 0.f; acc[nt][1] = 0.f; acc[nt][2] = 0.f; acc[nt][3] = 0.f;
  }
#pragma unroll
  for (int kt = 0; kt < 4; ++kt) {
    bfrag8 a = *(const bfrag8*)&As[(wv * 16 + lo) * 136 + kt * 32 + quad * 8];
    const unsigned short* pw = PWm + kt * 4096 + lane * 8;
#pragma unroll
    for (int nt = 0; nt < 8; ++nt) {
      bfrag8 b = *(const bfrag8*)(pw + nt * 512);
      acc[nt] = __builtin_amdgcn_mfma_f32_16x16x32_bf16(a, b, acc[nt], 0, 0, 0);
    }
  }
  __syncthreads();

  if (out_ext && !bf) {
    float* Co = (float*)Cp;
#pragma unroll
    for (int nt = 0; nt < 8; ++nt) {
      float b = bias[nt * 16 + lo];
#pragma unroll
      for (int reg = 0; reg < 4; ++reg) {
        int grow = row0 + wv * 16 + quad * 4 + reg;
        if (grow < N_NODES)
          Co[(size_t)grow * DIM + nt * 16 + lo] = acc[nt][reg] + b;
      }
    }
  } else {
#pragma unroll
    for (int nt = 0; nt < 8; ++nt) {
      float b = bias[nt * 16 + lo];
#pragma unroll
      for (int reg = 0; reg < 4; ++reg) {
        As[(wv * 16 + quad * 4 + reg) * 136 + nt * 16 + lo] =
            f2bf(acc[nt][reg] + b);
      }
    }
    __syncthreads();
    unsigned short* Co = (unsigned short*)Cp;
    for (int i = 0; i < 8; ++i) {
      int G = tid + i * 256;
      int lrow = G >> 5, ch = (G & 31) * 4;
      int grow = row0 + lrow;
      if (grow < N_NODES)
        *(ushort4*)(Co + (size_t)grow * DIM + ch) =
            *(const ushort4*)&As[lrow * 136 + ch];
    }
    if (do_stats) {
      int c = tid & 127, rh = tid >> 7;
      int rmax = N_NODES - row0;
      if (rmax > 64) rmax = 64;
      int rend = rh * 32 + 32;
      if (rend > rmax) rend = rmax;
      float s = 0.f, q = 0.f;
      for (int r = rh * 32; r < rend; ++r) {
        float v = bf2f(As[r * 136 + c]);
        s += v; q += v * v;
      }
      red_s[tid] = s; red_q[tid] = q;
      __syncthreads();
      if (tid < 128) {
        ps[blockIdx.x * 256 + tid] = red_s[tid] + red_s[tid + 128];
        ps[blockIdx.x * 256 + 128 + tid] = red_q[tid] + red_q[tid + 128];
      }
    }
  }
}

extern "C" void kernel_launch(void* const* d_in, const int* in_sizes, int n_in,
                              void* d_out, int out_size, void* d_ws, size_t ws_size,
                              hipStream_t stream) {
  const void* x  = d_in[0];
  const int* row = (const int*)d_in[1];
  const int* col = (const int*)d_in[2];

  const size_t ND = (size_t)N_NODES * DIM;
  unsigned short* agg = (unsigned short*)d_ws;        // ND bf16
  unsigned short* hA  = agg + ND;                     // ND bf16
  unsigned short* hB  = hA + ND;                      // ND bf16
  unsigned short* PW  = hB + ND;                      // 4*16384 bf16
  float* PV    = (float*)(PW + 4 * 16384);            // 10*128 fp32
  float* ps    = PV + 10 * DIM;                       // GEMM_GRID*256 fp32
  float* ss    = ps + GEMM_GRID * 256;                // 3*256 fp32
  int*   flag  = (int*)(ss + 3 * 256);                // 1 (+pad)
  int*   deg   = flag + 4;                            // N
  int*   bcnt  = deg + N_NODES;                       // NBUCK
  int*   pcnt  = bcnt + NBUCK;                        // 8 soft-barrier ctrs
  int*   offs  = pcnt + 8;                            // N+1
  int*   bsum  = offs + N_NODES + 1;                  // 256
  int*   bscan = bsum + 256;                          // 256
  int*   csr_col = bscan + 256;                       // E
  int*   suboffs = csr_col + N_EDGES;                 // N*4
  uint2* ebuf  = (uint2*)((((size_t)(suboffs + 4 * N_NODES)) + 15) & ~(size_t)15);

  float* c0_b1f = PV + 0 * DIM; float* c0_gf  = PV + 1 * DIM;
  float* c0_bef = PV + 2 * DIM; float* c0_b2f = PV + 3 * DIM;
  float* bn0_gf = PV + 4 * DIM; float* bn0_bef= PV + 5 * DIM;
  float* c1_b1f = PV + 6 * DIM; float* c1_gf  = PV + 7 * DIM;
  float* c1_bef = PV + 8 * DIM; float* c1_b2f = PV + 9 * DIM;

  detect_kernel<<<1, 64, 0, stream>>>((const unsigned short*)x, flag);

  PPtrs pp;
  pp.w[0] = d_in[3];  pp.w[1] = d_in[7];  pp.w[2] = d_in[11]; pp.w[3] = d_in[15];
  pp.v[0] = d_in[4];  pp.v[1] = d_in[5];  pp.v[2] = d_in[6];  pp.v[3] = d_in[8];
  pp.v[4] = d_in[9];  pp.v[5] = d_in[10]; pp.v[6] = d_in[12]; pp.v[7] = d_in[13];
  pp.v[8] = d_in[14]; pp.v[9] = d_in[16];
  prep_kernel<<<5, 256, 0, stream>>>(pp, PW, PV, flag);

  hipMemsetAsync(deg, 0, (N_NODES + NBUCK + 8) * sizeof(int), stream);

  // ---- CSR build ----
  binA_kernel<<<BINA_BLOCKS, 256, 0, stream>>>(row, col, deg, bcnt, ebuf);
  bsum_kernel<<<NB, 256, 0, stream>>>(deg, bsum);
  bscan_kernel<<<1, 256, 0, stream>>>(bsum, bscan);
  offs_kernel<<<NB, 256, 0, stream>>>(deg, bscan, offs);
  binB_kernel<<<NBUCK, 256, 0, stream>>>(offs, bcnt, ebuf, csr_col, suboffs);

  // ---- conv0 ----
  gather_pass_kernel<<<GW_BLOCKS, 256, 0, stream>>>(
      x, offs, suboffs, csr_col, nullptr, agg, flag, pcnt, 0);
  gemm_kernel<<<GEMM_GRID, 256, 0, stream>>>(
      x, agg, PW + 0 * 16384, c0_b1f, nullptr, hA, ps, flag,
      1, 1, 0, 0, 1);
  bn_fin_kernel<<<128, 256, 0, stream>>>(ps, c0_gf, c0_bef, ss + 0);
  gemm_kernel<<<GEMM_GRID, 256, 0, stream>>>(
      hA, nullptr, PW + 1 * 16384, c0_b2f, ss + 0, hB, ps, flag,
      0, 0, 1, 0, 1);
  bn_fin_kernel<<<128, 256, 0, stream>>>(ps, bn0_gf, bn0_bef, ss + 256);

  // ---- conv1 ----
  gather_pass_kernel<<<GW_BLOCKS, 256, 0, stream>>>(
      hB, offs, suboffs, csr_col, ss + 256, agg, flag, pcnt + 4, 1);
  gemm_kernel<<<GEMM_GRID, 256, 0, stream>>>(
      hB, agg, PW + 2 * 16384, c1_b1f, ss + 256, hA, ps, flag,
      0, 1, 1, 0, 1);
  bn_fin_kernel<<<128, 256, 0, stream>>>(ps, c1_gf, c1_bef, ss + 512);
  gemm_kernel<<<GEMM_GRID, 256, 0, stream>>>(
      hA, nullptr, PW + 3 * 16384, c1_b2f, ss + 512, d_out, nullptr, flag,
      0, 0, 1, 1, 0);
}

// Round 2
// 348.669 us; speedup vs baseline: 2.4197x; 2.4197x over previous
//
#include <hip/hip_runtime.h>

// GIN 2-layer forward, MI355X (gfx950). Round 13:
//  - gather reverted to round-11 structure (wave = 1 node, unroll-16,
//    12500 blocks): proven 55us/3.45TB/s, high MLP.
//  - KEPT from round 12: binB orders each node's adjacency by col-block
//    (4 blocks of 12500 nodes = 3.2MB bf16 rows each, fits XCD L2).
//    Co-resident waves then sweep col-blocks loosely in phase -> smaller
//    instantaneous read working set -> better L2 hit rate, zero cost.
//  - persistent/soft-barrier machinery removed (round 12 post-mortem:
//    occupancy 46% < 50% needed for co-residency -> barriers spun out;
//    4-edge sub-segments collapsed MLP to ~4 outstanding loads).

#define N_NODES 50000
#define N_EDGES 800000
#define DIM 128
#define BN_EPS 1e-5f
#define NB 196                  // ceil(N_NODES/256) scan blocks
#define GEMM_GRID 782           // ceil(N_NODES/64)
#define NBUCK 256
#define NPB 196                 // nodes per bucket
#define BCAP 4096               // max edges per bucket
#define BINA_BLOCKS 128
#define EPB (N_EDGES / BINA_BLOCKS)
#define CBLK 12500              // col-block width (4 blocks, 3.2MB bf16 each)

using bfrag8 = __attribute__((ext_vector_type(8))) short;
using accf4  = __attribute__((ext_vector_type(4))) float;

__device__ __forceinline__ float bf2f(unsigned short u) {
  union { unsigned u32; float f; } c;
  c.u32 = ((unsigned)u) << 16;
  return c.f;
}
__device__ __forceinline__ unsigned short f2bf(float f) {
  union { float f; unsigned u32; } c;
  c.f = f;
  unsigned u = c.u32;
  return (unsigned short)((u + 0x7fffu + ((u >> 16) & 1u)) >> 16);  // RNE
}

// ---- dtype detector ----
__global__ void detect_kernel(const unsigned short* __restrict__ xs,
                              int* __restrict__ flag) {
  __shared__ int oks[64];
  int t = threadIdx.x;
  unsigned short u = xs[t * 2];
  int e = (u >> 7) & 0xFF;
  oks[t] = ((e >= 96 && e <= 134) || ((u & 0x7FFFu) == 0)) ? 1 : 0;
  __syncthreads();
  if (t == 0) {
    int c = 0;
    for (int i = 0; i < 64; ++i) c += oks[i];
    *flag = (c >= 56) ? 1 : 0;  // 1 = bf16, 0 = fp32
  }
}

// ---- prep: pack weights into MFMA B-frag layout + convert vectors ----
struct PPtrs { const void* w[4]; const void* v[10]; };

__global__ __launch_bounds__(256) void prep_kernel(
    PPtrs pp, unsigned short* __restrict__ PW, float* __restrict__ PV,
    const int* __restrict__ flagp) {
  int bf = *flagp;
  if (blockIdx.x < 4) {
    int mat = blockIdx.x;
    const void* src = pp.w[mat];
    unsigned short* dst = PW + (size_t)mat * 16384;
    for (int f = threadIdx.x; f < 2048; f += 256) {
      int kt = f >> 9, nt = (f >> 6) & 7, lane = f & 63;
      int kbase = kt * 32 + (lane >> 4) * 8;
      int n = nt * 16 + (lane & 15);
      unsigned short tmp[8];
      for (int j = 0; j < 8; ++j) {
        int idx = (kbase + j) * DIM + n;
        if (bf) tmp[j] = ((const unsigned short*)src)[idx];
        else    tmp[j] = f2bf(((const float*)src)[idx]);
      }
      for (int j = 0; j < 8; ++j) dst[f * 8 + j] = tmp[j];
    }
  } else {
    for (int j = threadIdx.x; j < 10 * DIM; j += 256) {
      int vec = j >> 7, idx = j & 127;
      float v;
      if (bf) v = bf2f(((const unsigned short*)pp.v[vec])[idx]);
      else    v = ((const float*)pp.v[vec])[idx];
      PV[j] = v;
    }
  }
}

// ================= CSR build =================
__global__ __launch_bounds__(256) void binA_kernel(
    const int* __restrict__ row, const int* __restrict__ col,
    int* __restrict__ deg, int* __restrict__ bcnt, uint2* __restrict__ ebuf) {
  __shared__ int hist[NBUCK];
  __shared__ int base[NBUCK];
  int t = threadIdx.x;
  int e0 = blockIdx.x * EPB;
  hist[t] = 0;
  __syncthreads();
  for (int i = t; i < EPB; i += 256) {
    int r = row[e0 + i];
    atomicAdd(&deg[r], 1);
    atomicAdd(&hist[r / NPB], 1);
  }
  __syncthreads();
  base[t] = atomicAdd(&bcnt[t], hist[t]);
  hist[t] = 0;
  __syncthreads();
  for (int i = t; i < EPB; i += 256) {
    int r = row[e0 + i];
    int c = col[e0 + i];
    int b = r / NPB;
    int rank = atomicAdd(&hist[b], 1);
    ebuf[(size_t)b * BCAP + base[b] + rank] = make_uint2((unsigned)r, (unsigned)c);
  }
}

__global__ __launch_bounds__(256) void bsum_kernel(
    const int* __restrict__ deg, int* __restrict__ bsum) {
  __shared__ int s[256];
  int i = blockIdx.x * 256 + threadIdx.x;
  s[threadIdx.x] = (i < N_NODES) ? deg[i] : 0;
  __syncthreads();
  for (int d = 128; d > 0; d >>= 1) {
    if (threadIdx.x < d) s[threadIdx.x] += s[threadIdx.x + d];
    __syncthreads();
  }
  if (threadIdx.x == 0) bsum[blockIdx.x] = s[0];
}

__global__ __launch_bounds__(256) void bscan_kernel(
    const int* __restrict__ bsum, int* __restrict__ bscan) {
  __shared__ int s[256];
  int t = threadIdx.x;
  int v = (t < NB) ? bsum[t] : 0;
  s[t] = v;
  __syncthreads();
  for (int d = 1; d < 256; d <<= 1) {
    int tv = (t >= d) ? s[t - d] : 0;
    __syncthreads();
    s[t] += tv;
    __syncthreads();
  }
  if (t < NB) bscan[t] = s[t] - v;  // exclusive
}

__global__ __launch_bounds__(256) void offs_kernel(
    const int* __restrict__ deg, const int* __restrict__ bscan,
    int* __restrict__ offs) {
  __shared__ int s[256];
  int t = threadIdx.x;
  int i = blockIdx.x * 256 + t;
  int v = (i < N_NODES) ? deg[i] : 0;
  s[t] = v;
  __syncthreads();
  for (int d = 1; d < 256; d <<= 1) {
    int tv = (t >= d) ? s[t - d] : 0;
    __syncthreads();
    s[t] += tv;
    __syncthreads();
  }
  if (i < N_NODES) {
    int excl = bscan[blockIdx.x] + s[t] - v;
    offs[i] = excl;
    if (i == N_NODES - 1) offs[N_NODES] = excl + v;
  }
}

// binB: scatter into CSR with each node's neighbor list ordered by
// col-block (4-way per-node counting sort). Ordering is perf-only:
// co-resident gather waves sweep col-blocks loosely in phase.
__global__ __launch_bounds__(256) void binB_kernel(
    const int* __restrict__ offs, const int* __restrict__ bcnt,
    const uint2* __restrict__ ebuf, int* __restrict__ csr_col) {
  __shared__ int cur4[NPB * 4];
  __shared__ int seg[BCAP];
  int b = blockIdx.x;
  int nb = b * NPB;
  int nend = nb + NPB;
  if (nend > N_NODES) nend = N_NODES;
  int nn = nend - nb;
  int segbase = offs[nb];
  int seglen = offs[nend] - segbase;
  int cnt = bcnt[b];
  const uint2* eb = ebuf + (size_t)b * BCAP;
  for (int i = threadIdx.x; i < nn * 4; i += 256) cur4[i] = 0;
  __syncthreads();
  // count per (node, col-block)
  for (int i = threadIdx.x; i < cnt; i += 256) {
    uint2 e = eb[i];
    int blk = (int)e.y / CBLK;
    atomicAdd(&cur4[(e.x - (unsigned)nb) * 4 + blk], 1);
  }
  __syncthreads();
  // per-node 4-way prefix -> local running starts
  for (int t = threadIdx.x; t < nn; t += 256) {
    int run = offs[nb + t] - segbase;
    int c0 = cur4[t * 4 + 0], c1 = cur4[t * 4 + 1];
    int c2 = cur4[t * 4 + 2];
    cur4[t * 4 + 0] = run;
    cur4[t * 4 + 1] = run + c0;
    cur4[t * 4 + 2] = run + c0 + c1;
    cur4[t * 4 + 3] = run + c0 + c1 + c2;
  }
  __syncthreads();
  // scatter in (node, blk) order
  for (int i = threadIdx.x; i < cnt; i += 256) {
    uint2 e = eb[i];
    int blk = (int)e.y / CBLK;
    int slot = atomicAdd(&cur4[(e.x - (unsigned)nb) * 4 + blk], 1);
    seg[slot] = (int)e.y;
  }
  __syncthreads();
  for (int i = threadIdx.x; i < seglen; i += 256)
    csr_col[segbase + i] = seg[i];
}

// ================= full-row gather, unroll-16 =================
// Wave = 1 node; lane owns 2 channels (4B) => one wave instruction reads the
// whole 256B feature row of one neighbor. Unroll-16 = a full mean-degree
// node in one latency exposure. Index loads are wave-uniform -> scalar.
// mode 0: plain sum (src dtype per flag); mode 1: relu(v*sc+sh), bf16 src.
__global__ __launch_bounds__(256) void gather_row_kernel(
    const void* __restrict__ src, const int* __restrict__ offs,
    const int* __restrict__ csr_col, const float* __restrict__ ss,
    unsigned short* __restrict__ agg, const int* __restrict__ flagp,
    int mode) {
  int node = blockIdx.x * 4 + (threadIdx.x >> 6);
  if (node >= N_NODES) return;
  int lane = threadIdx.x & 63;
  int ch = lane * 2;
  int start = offs[node], end = offs[node + 1];
  float a0 = 0.f, a1 = 0.f;
  int bf = *flagp;
  float sc0 = 0.f, sc1 = 0.f, sh0 = 0.f, sh1 = 0.f;
  if (mode == 1) {
    sc0 = ss[ch]; sc1 = ss[ch + 1];
    sh0 = ss[DIM + ch]; sh1 = ss[DIM + ch + 1];
  }

  if (mode == 1 || bf) {
    const unsigned short* h = (const unsigned short*)src;
    int j = start;
    for (; j + 15 < end; j += 16) {
      int ix[16];
#pragma unroll
      for (int k = 0; k < 16; ++k) ix[k] = csr_col[j + k];
      unsigned u[16];
#pragma unroll
      for (int k = 0; k < 16; ++k)
        u[k] = *(const unsigned*)(h + (size_t)ix[k] * DIM + ch);
      if (mode == 1) {
#pragma unroll
        for (int k = 0; k < 16; ++k) {
          a0 += fmaxf(bf2f((unsigned short)u[k]) * sc0 + sh0, 0.f);
          a1 += fmaxf(bf2f((unsigned short)(u[k] >> 16)) * sc1 + sh1, 0.f);
        }
      } else {
#pragma unroll
        for (int k = 0; k < 16; ++k) {
          a0 += bf2f((unsigned short)u[k]);
          a1 += bf2f((unsigned short)(u[k] >> 16));
        }
      }
    }
    if (j + 7 < end) {
      int ix[8];
#pragma unroll
      for (int k = 0; k < 8; ++k) ix[k] = csr_col[j + k];
      unsigned u[8];
#pragma unroll
      for (int k = 0; k < 8; ++k)
        u[k] = *(const unsigned*)(h + (size_t)ix[k] * DIM + ch);
#pragma unroll
      for (int k = 0; k < 8; ++k) {
        if (mode == 1) {
          a0 += fmaxf(bf2f((unsigned short)u[k]) * sc0 + sh0, 0.f);
          a1 += fmaxf(bf2f((unsigned short)(u[k] >> 16)) * sc1 + sh1, 0.f);
        } else {
          a0 += bf2f((unsigned short)u[k]);
          a1 += bf2f((unsigned short)(u[k] >> 16));
        }
      }
      j += 8;
    }
    if (j + 3 < end) {
      int ix[4];
#pragma unroll
      for (int k = 0; k < 4; ++k) ix[k] = csr_col[j + k];
      unsigned u[4];
#pragma unroll
      for (int k = 0; k < 4; ++k)
        u[k] = *(const unsigned*)(h + (size_t)ix[k] * DIM + ch);
#pragma unroll
      for (int k = 0; k < 4; ++k) {
        if (mode == 1) {
          a0 += fmaxf(bf2f((unsigned short)u[k]) * sc0 + sh0, 0.f);
          a1 += fmaxf(bf2f((unsigned short)(u[k] >> 16)) * sc1 + sh1, 0.f);
        } else {
          a0 += bf2f((unsigned short)u[k]);
          a1 += bf2f((unsigned short)(u[k] >> 16));
        }
      }
      j += 4;
    }
    for (; j < end; ++j) {
      unsigned u = *(const unsigned*)(h + (size_t)csr_col[j] * DIM + ch);
      if (mode == 1) {
        a0 += fmaxf(bf2f((unsigned short)u) * sc0 + sh0, 0.f);
        a1 += fmaxf(bf2f((unsigned short)(u >> 16)) * sc1 + sh1, 0.f);
      } else {
        a0 += bf2f((unsigned short)u);
        a1 += bf2f((unsigned short)(u >> 16));
      }
    }
  } else {
    const float* x = (const float*)src;
    int j = start;
    for (; j + 7 < end; j += 8) {
      int ix[8];
#pragma unroll
      for (int k = 0; k < 8; ++k) ix[k] = csr_col[j + k];
#pragma unroll
      for (int k = 0; k < 8; ++k) {
        float2 v = *(const float2*)(x + (size_t)ix[k] * DIM + ch);
        a0 += v.x; a1 += v.y;
      }
    }
    for (; j < end; ++j) {
      float2 v = *(const float2*)(x + (size_t)csr_col[j] * DIM + ch);
      a0 += v.x; a1 += v.y;
    }
  }
  unsigned o = (unsigned)f2bf(a0) | ((unsigned)f2bf(a1) << 16);
  *(unsigned*)(agg + (size_t)node * DIM + ch) = o;
}

// ---- BN finalize: one block per channel ----
__global__ __launch_bounds__(256) void bn_fin_kernel(
    const float* __restrict__ ps, const float* __restrict__ g,
    const float* __restrict__ be, float* __restrict__ ss) {
  __shared__ float s2[256], q2[256];
  int c = blockIdx.x;
  int t = threadIdx.x;
  float s = 0.f, q = 0.f;
  for (int b = t; b < GEMM_GRID; b += 256) {
    s += ps[b * 256 + c];
    q += ps[b * 256 + 128 + c];
  }
  s2[t] = s; q2[t] = q;
  __syncthreads();
  for (int d = 128; d > 0; d >>= 1) {
    if (t < d) { s2[t] += s2[t + d]; q2[t] += q2[t + d]; }
    __syncthreads();
  }
  if (t == 0) {
    const float invN = 1.0f / (float)N_NODES;
    float m = s2[0] * invN;
    float v = q2[0] * invN - m * m;
    float scale = g[c] * rsqrtf(v + BN_EPS);
    ss[c] = scale;
    ss[DIM + c] = be[c] - m * scale;
  }
}

// ================= MFMA GEMM =================
__global__ __launch_bounds__(256) void gemm_kernel(
    const void* __restrict__ Ap, const unsigned short* __restrict__ agg,
    const unsigned short* __restrict__ PWm, const float* __restrict__ bias,
    const float* __restrict__ ss, void* __restrict__ Cp,
    float* __restrict__ ps, const int* __restrict__ flagp,
    int a_ext, int add_agg, int transform, int out_ext, int do_stats) {
  __shared__ unsigned short As[64 * 136];
  __shared__ float red_s[256];
  __shared__ float red_q[256];
  const int tid = threadIdx.x;
  const int row0 = blockIdx.x * 64;
  const int bf = *flagp;

  for (int i = 0; i < 8; ++i) {
    int G = tid + i * 256;
    int lrow = G >> 5;
    int ch = (G & 31) * 4;
    int grow = row0 + lrow;
    float4 v = make_float4(0.f, 0.f, 0.f, 0.f);
    if (grow < N_NODES) {
      if (a_ext && !bf) {
        v = *(const float4*)((const float*)Ap + (size_t)grow * DIM + ch);
      } else {
        ushort4 u = *(const ushort4*)((const unsigned short*)Ap +
                                      (size_t)grow * DIM + ch);
        v = make_float4(bf2f(u.x), bf2f(u.y), bf2f(u.z), bf2f(u.w));
      }
      if (transform) {
        float4 sc = *(const float4*)(ss + ch);
        float4 sh = *(const float4*)(ss + DIM + ch);
        v.x = fmaxf(v.x * sc.x + sh.x, 0.f);
        v.y = fmaxf(v.y * sc.y + sh.y, 0.f);
        v.z = fmaxf(v.z * sc.z + sh.z, 0.f);
        v.w = fmaxf(v.w * sc.w + sh.w, 0.f);
      }
      if (add_agg) {
        ushort4 au = *(const ushort4*)(agg + (size_t)grow * DIM + ch);
        v.x += bf2f(au.x); v.y += bf2f(au.y);
        v.z += bf2f(au.z); v.w += bf2f(au.w);
      }
    }
    ushort4 o;
    o.x = f2bf(v.x); o.y = f2bf(v.y); o.z = f2bf(v.z); o.w = f2bf(v.w);
    *(ushort4*)&As[lrow * 136 + ch] = o;
  }
  __syncthreads();

  const int wv = tid >> 6, lane = tid & 63;
  const int quad = lane >> 4, lo = lane & 15;
  accf4 acc[8];
#pragma unroll
  for (int nt = 0; nt < 8; ++nt) {
    acc[nt][0] = 0.f; acc[nt][1] = 0.f; acc[nt][2] = 0.f; acc[nt][3] = 0.f;
  }
#pragma unroll
  for (int kt = 0; kt < 4; ++kt) {
    bfrag8 a = *(const bfrag8*)&As[(wv * 16 + lo) * 136 + kt * 32 + quad * 8];
    const unsigned short* pw = PWm + kt * 4096 + lane * 8;
#pragma unroll
    for (int nt = 0; nt < 8; ++nt) {
      bfrag8 b = *(const bfrag8*)(pw + nt * 512);
      acc[nt] = __builtin_amdgcn_mfma_f32_16x16x32_bf16(a, b, acc[nt], 0, 0, 0);
    }
  }
  __syncthreads();

  if (out_ext && !bf) {
    float* Co = (float*)Cp;
#pragma unroll
    for (int nt = 0; nt < 8; ++nt) {
      float b = bias[nt * 16 + lo];
#pragma unroll
      for (int reg = 0; reg < 4; ++reg) {
        int grow = row0 + wv * 16 + quad * 4 + reg;
        if (grow < N_NODES)
          Co[(size_t)grow * DIM + nt * 16 + lo] = acc[nt][reg] + b;
      }
    }
  } else {
#pragma unroll
    for (int nt = 0; nt < 8; ++nt) {
      float b = bias[nt * 16 + lo];
#pragma unroll
      for (int reg = 0; reg < 4; ++reg) {
        As[(wv * 16 + quad * 4 + reg) * 136 + nt * 16 + lo] =
            f2bf(acc[nt][reg] + b);
      }
    }
    __syncthreads();
    unsigned short* Co = (unsigned short*)Cp;
    for (int i = 0; i < 8; ++i) {
      int G = tid + i * 256;
      int lrow = G >> 5, ch = (G & 31) * 4;
      int grow = row0 + lrow;
      if (grow < N_NODES)
        *(ushort4*)(Co + (size_t)grow * DIM + ch) =
            *(const ushort4*)&As[lrow * 136 + ch];
    }
    if (do_stats) {
      int c = tid & 127, rh = tid >> 7;
      int rmax = N_NODES - row0;
      if (rmax > 64) rmax = 64;
      int rend = rh * 32 + 32;
      if (rend > rmax) rend = rmax;
      float s = 0.f, q = 0.f;
      for (int r = rh * 32; r < rend; ++r) {
        float v = bf2f(As[r * 136 + c]);
        s += v; q += v * v;
      }
      red_s[tid] = s; red_q[tid] = q;
      __syncthreads();
      if (tid < 128) {
        ps[blockIdx.x * 256 + tid] = red_s[tid] + red_s[tid + 128];
        ps[blockIdx.x * 256 + 128 + tid] = red_q[tid] + red_q[tid + 128];
      }
    }
  }
}

extern "C" void kernel_launch(void* const* d_in, const int* in_sizes, int n_in,
                              void* d_out, int out_size, void* d_ws, size_t ws_size,
                              hipStream_t stream) {
  const void* x  = d_in[0];
  const int* row = (const int*)d_in[1];
  const int* col = (const int*)d_in[2];

  const size_t ND = (size_t)N_NODES * DIM;
  unsigned short* agg = (unsigned short*)d_ws;        // ND bf16
  unsigned short* hA  = agg + ND;                     // ND bf16
  unsigned short* hB  = hA + ND;                      // ND bf16
  unsigned short* PW  = hB + ND;                      // 4*16384 bf16
  float* PV    = (float*)(PW + 4 * 16384);            // 10*128 fp32
  float* ps    = PV + 10 * DIM;                       // GEMM_GRID*256 fp32
  float* ss    = ps + GEMM_GRID * 256;                // 3*256 fp32
  int*   flag  = (int*)(ss + 3 * 256);                // 1 (+pad)
  int*   deg   = flag + 4;                            // N
  int*   bcnt  = deg + N_NODES;                       // NBUCK
  int*   offs  = bcnt + NBUCK;                        // N+1
  int*   bsum  = offs + N_NODES + 1;                  // 256
  int*   bscan = bsum + 256;                          // 256
  int*   csr_col = bscan + 256;                       // E
  uint2* ebuf  = (uint2*)((((size_t)(csr_col + N_EDGES)) + 15) & ~(size_t)15);

  float* c0_b1f = PV + 0 * DIM; float* c0_gf  = PV + 1 * DIM;
  float* c0_bef = PV + 2 * DIM; float* c0_b2f = PV + 3 * DIM;
  float* bn0_gf = PV + 4 * DIM; float* bn0_bef= PV + 5 * DIM;
  float* c1_b1f = PV + 6 * DIM; float* c1_gf  = PV + 7 * DIM;
  float* c1_bef = PV + 8 * DIM; float* c1_b2f = PV + 9 * DIM;

  const int grow_grid = (N_NODES + 3) / 4;  // 12500

  detect_kernel<<<1, 64, 0, stream>>>((const unsigned short*)x, flag);

  PPtrs pp;
  pp.w[0] = d_in[3];  pp.w[1] = d_in[7];  pp.w[2] = d_in[11]; pp.w[3] = d_in[15];
  pp.v[0] = d_in[4];  pp.v[1] = d_in[5];  pp.v[2] = d_in[6];  pp.v[3] = d_in[8];
  pp.v[4] = d_in[9];  pp.v[5] = d_in[10]; pp.v[6] = d_in[12]; pp.v[7] = d_in[13];
  pp.v[8] = d_in[14]; pp.v[9] = d_in[16];
  prep_kernel<<<5, 256, 0, stream>>>(pp, PW, PV, flag);

  hipMemsetAsync(deg, 0, (N_NODES + NBUCK) * sizeof(int), stream);

  // ---- CSR build ----
  binA_kernel<<<BINA_BLOCKS, 256, 0, stream>>>(row, col, deg, bcnt, ebuf);
  bsum_kernel<<<NB, 256, 0, stream>>>(deg, bsum);
  bscan_kernel<<<1, 256, 0, stream>>>(bsum, bscan);
  offs_kernel<<<NB, 256, 0, stream>>>(deg, bscan, offs);
  binB_kernel<<<NBUCK, 256, 0, stream>>>(offs, bcnt, ebuf, csr_col);

  // ---- conv0 ----
  gather_row_kernel<<<grow_grid, 256, 0, stream>>>(x, offs, csr_col, nullptr,
                                                   agg, flag, 0);
  gemm_kernel<<<GEMM_GRID, 256, 0, stream>>>(
      x, agg, PW + 0 * 16384, c0_b1f, nullptr, hA, ps, flag,
      1, 1, 0, 0, 1);
  bn_fin_kernel<<<128, 256, 0, stream>>>(ps, c0_gf, c0_bef, ss + 0);
  gemm_kernel<<<GEMM_GRID, 256, 0, stream>>>(
      hA, nullptr, PW + 1 * 16384, c0_b2f, ss + 0, hB, ps, flag,
      0, 0, 1, 0, 1);
  bn_fin_kernel<<<128, 256, 0, stream>>>(ps, bn0_gf, bn0_bef, ss + 256);

  // ---- conv1 ----
  gather_row_kernel<<<grow_grid, 256, 0, stream>>>(hB, offs, csr_col, ss + 256,
                                                   agg, flag, 1);
  gemm_kernel<<<GEMM_GRID, 256, 0, stream>>>(
      hB, agg, PW + 2 * 16384, c1_b1f, ss + 256, hA, ps, flag,
      0, 1, 1, 0, 1);
  bn_fin_kernel<<<128, 256, 0, stream>>>(ps, c1_gf, c1_bef, ss + 512);
  gemm_kernel<<<GEMM_GRID, 256, 0, stream>>>(
      hA, nullptr, PW + 3 * 16384, c1_b2f, ss + 512, d_out, nullptr, flag,
      0, 0, 1, 1, 0);
}

// Round 3
// 333.779 us; speedup vs baseline: 2.5276x; 1.0446x over previous
//
#include <hip/hip_runtime.h>

// GIN 2-layer forward, MI355X (gfx950). Round 14: dispatch fusion.
//  17 -> 9 dispatches:
//  - detect fused into prep (per-block self-detection).
//  - deg/bcnt zeroing fused into prep (blocks 5..39).
//  - bsum/bscan/offs fused into binB (redundant 256-wide bcnt scan per
//    block + local degree scan -> offs written by binB).
//  - 3x bn_fin removed: gemm0/1/2 atomically accumulate channel sum/sumsq
//    into 16-slotted stats buffers; consumers (gemm1/2/3, gather1) reduce
//    slots into LDS scale/shift at kernel start.
//  - gather kernel unchanged from round 11/13 (proven 55us, 3.4TB/s).

#define N_NODES 50000
#define N_EDGES 800000
#define DIM 128
#define BN_EPS 1e-5f
#define GEMM_GRID 782           // ceil(N_NODES/64)
#define NBUCK 256
#define NPB 196                 // nodes per bucket
#define BCAP 4096               // max edges per bucket
#define BINA_BLOCKS 128
#define EPB (N_EDGES / BINA_BLOCKS)
#define CBLK 12500              // col-block width (kept from r13, perf-neutral)
#define NSLOT 16                // stats atomic slots

using bfrag8 = __attribute__((ext_vector_type(8))) short;
using accf4  = __attribute__((ext_vector_type(4))) float;

__device__ __forceinline__ float bf2f(unsigned short u) {
  union { unsigned u32; float f; } c;
  c.u32 = ((unsigned)u) << 16;
  return c.f;
}
__device__ __forceinline__ unsigned short f2bf(float f) {
  union { float f; unsigned u32; } c;
  c.f = f;
  unsigned u = c.u32;
  return (unsigned short)((u + 0x7fffu + ((u >> 16) & 1u)) >> 16);  // RNE
}

// ---- prep: detect dtype, pack weights, convert vectors, zero scratch ----
struct PPtrs { const void* xs; const void* w[4]; const void* v[10]; };

__global__ __launch_bounds__(256) void prep_kernel(
    PPtrs pp, unsigned short* __restrict__ PW, float* __restrict__ PV,
    int* __restrict__ flag, float* __restrict__ ps2, int* __restrict__ deg) {
  __shared__ int oks[64];
  __shared__ int bfs;
  int t = threadIdx.x;
  // per-block dtype self-detection (64 samples of x)
  if (t < 64) {
    unsigned short u = ((const unsigned short*)pp.xs)[t * 2];
    int e = (u >> 7) & 0xFF;
    oks[t] = ((e >= 96 && e <= 134) || ((u & 0x7FFFu) == 0)) ? 1 : 0;
  }
  __syncthreads();
  if (t == 0) {
    int c = 0;
    for (int i = 0; i < 64; ++i) c += oks[i];
    bfs = (c >= 56) ? 1 : 0;
  }
  __syncthreads();
  int bf = bfs;
  int b = blockIdx.x;

  if (b < 4) {
    // pack weight matrix b into MFMA B-frag layout
    const void* src = pp.w[b];
    unsigned short* dst = PW + (size_t)b * 16384;
    for (int f = t; f < 2048; f += 256) {
      int kt = f >> 9, nt = (f >> 6) & 7, lane = f & 63;
      int kbase = kt * 32 + (lane >> 4) * 8;
      int n = nt * 16 + (lane & 15);
      unsigned short tmp[8];
      for (int j = 0; j < 8; ++j) {
        int idx = (kbase + j) * DIM + n;
        if (bf) tmp[j] = ((const unsigned short*)src)[idx];
        else    tmp[j] = f2bf(((const float*)src)[idx]);
      }
      for (int j = 0; j < 8; ++j) dst[f * 8 + j] = tmp[j];
    }
  } else if (b == 4) {
    // vectors, flag, zero stats slots
    for (int j = t; j < 10 * DIM; j += 256) {
      int vec = j >> 7, idx = j & 127;
      float v;
      if (bf) v = bf2f(((const unsigned short*)pp.v[vec])[idx]);
      else    v = ((const float*)pp.v[vec])[idx];
      PV[j] = v;
    }
    if (t == 0) *flag = bf;
    for (int j = t; j < 3 * NSLOT * 256; j += 256) ps2[j] = 0.f;
  } else {
    // blocks 5..39 zero deg[N] + bcnt[NBUCK] (contiguous)
    const int total = N_NODES + NBUCK;
    for (int i = (b - 5) * 256 + t; i < total; i += 35 * 256) deg[i] = 0;
  }
}

// ================= CSR build =================
__global__ __launch_bounds__(256) void binA_kernel(
    const int* __restrict__ row, const int* __restrict__ col,
    int* __restrict__ deg, int* __restrict__ bcnt, uint2* __restrict__ ebuf) {
  __shared__ int hist[NBUCK];
  __shared__ int base[NBUCK];
  int t = threadIdx.x;
  int e0 = blockIdx.x * EPB;
  hist[t] = 0;
  __syncthreads();
  for (int i = t; i < EPB; i += 256) {
    int r = row[e0 + i];
    atomicAdd(&deg[r], 1);
    atomicAdd(&hist[r / NPB], 1);
  }
  __syncthreads();
  base[t] = atomicAdd(&bcnt[t], hist[t]);
  hist[t] = 0;
  __syncthreads();
  for (int i = t; i < EPB; i += 256) {
    int r = row[e0 + i];
    int c = col[e0 + i];
    int b = r / NPB;
    int rank = atomicAdd(&hist[b], 1);
    ebuf[(size_t)b * BCAP + base[b] + rank] = make_uint2((unsigned)r, (unsigned)c);
  }
}

// binB: per-block redundant scan of bcnt -> segbase; local degree scan ->
// offs; col-block-ordered scatter into csr_col.
__global__ __launch_bounds__(256) void binB_kernel(
    const int* __restrict__ deg, const int* __restrict__ bcnt,
    const uint2* __restrict__ ebuf, int* __restrict__ csr_col,
    int* __restrict__ offs) {
  __shared__ int sc[256];        // bcnt inclusive scan
  __shared__ int dg[256];        // local degree inclusive scan
  __shared__ int cur4[NPB * 4];
  __shared__ int seg[BCAP];
  int b = blockIdx.x;
  int t = threadIdx.x;

  sc[t] = bcnt[t];
  __syncthreads();
  for (int d = 1; d < 256; d <<= 1) {
    int v = (t >= d) ? sc[t - d] : 0;
    __syncthreads();
    sc[t] += v;
    __syncthreads();
  }
  int segbase = (b == 0) ? 0 : sc[b - 1];

  int nb = b * NPB;
  int nend = nb + NPB;
  if (nend > N_NODES) nend = N_NODES;
  int nn = nend - nb;

  int myd = (t < nn) ? deg[nb + t] : 0;
  dg[t] = myd;
  __syncthreads();
  for (int d = 1; d < 256; d <<= 1) {
    int v = (t >= d) ? dg[t - d] : 0;
    __syncthreads();
    dg[t] += v;
    __syncthreads();
  }
  int excl = dg[t] - myd;       // local exclusive prefix (valid for t < nn)
  if (t < nn) offs[nb + t] = segbase + excl;
  if (b == NBUCK - 1 && t == 0) offs[N_NODES] = N_EDGES;

  int cnt = bcnt[b];
  const uint2* eb = ebuf + (size_t)b * BCAP;
  for (int i = t; i < nn * 4; i += 256) cur4[i] = 0;
  __syncthreads();
  // count per (node, col-block)
  for (int i = t; i < cnt; i += 256) {
    uint2 e = eb[i];
    int blk = (int)e.y / CBLK;
    atomicAdd(&cur4[(e.x - (unsigned)nb) * 4 + blk], 1);
  }
  __syncthreads();
  // per-node 4-way prefix -> local running starts (t<nn: nn<=196<256)
  if (t < nn) {
    int run = excl;
    int c0 = cur4[t * 4 + 0], c1 = cur4[t * 4 + 1];
    int c2 = cur4[t * 4 + 2];
    cur4[t * 4 + 0] = run;
    cur4[t * 4 + 1] = run + c0;
    cur4[t * 4 + 2] = run + c0 + c1;
    cur4[t * 4 + 3] = run + c0 + c1 + c2;
  }
  __syncthreads();
  // scatter in (node, blk) order
  for (int i = t; i < cnt; i += 256) {
    uint2 e = eb[i];
    int blk = (int)e.y / CBLK;
    int slot = atomicAdd(&cur4[(e.x - (unsigned)nb) * 4 + blk], 1);
    seg[slot] = (int)e.y;
  }
  __syncthreads();
  for (int i = t; i < cnt; i += 256)
    csr_col[segbase + i] = seg[i];
}

// ================= full-row gather, unroll-16 =================
// Wave = 1 node; lane owns 2 channels (4B) => one wave instruction reads the
// whole 256B feature row of one neighbor. mode 0: plain sum; mode 1:
// relu(v*sc+sh) with scale/shift derived from slotted stats + g/be.
__global__ __launch_bounds__(256) void gather_row_kernel(
    const void* __restrict__ src, const int* __restrict__ offs,
    const int* __restrict__ csr_col, const float* __restrict__ stats_in,
    const float* __restrict__ gv, const float* __restrict__ bev,
    unsigned short* __restrict__ agg, const int* __restrict__ flagp,
    int mode) {
  __shared__ float ssl[256];
  int tid = threadIdx.x;
  if (mode == 1) {
    if (tid < 128) {
      float s = 0.f, q = 0.f;
#pragma unroll
      for (int k = 0; k < NSLOT; ++k) {
        s += stats_in[k * 256 + tid];
        q += stats_in[k * 256 + 128 + tid];
      }
      const float invN = 1.0f / (float)N_NODES;
      float m = s * invN;
      float v = q * invN - m * m;
      float scv = gv[tid] * rsqrtf(v + BN_EPS);
      ssl[tid] = scv;
      ssl[128 + tid] = bev[tid] - m * scv;
    }
    __syncthreads();
  }

  int node = blockIdx.x * 4 + (tid >> 6);
  if (node >= N_NODES) return;
  int lane = tid & 63;
  int ch = lane * 2;
  int start = offs[node], end = offs[node + 1];
  float a0 = 0.f, a1 = 0.f;
  int bf = *flagp;
  float sc0 = 0.f, sc1 = 0.f, sh0 = 0.f, sh1 = 0.f;
  if (mode == 1) {
    sc0 = ssl[ch]; sc1 = ssl[ch + 1];
    sh0 = ssl[128 + ch]; sh1 = ssl[128 + ch + 1];
  }

  if (mode == 1 || bf) {
    const unsigned short* h = (const unsigned short*)src;
    int j = start;
    for (; j + 15 < end; j += 16) {
      int ix[16];
#pragma unroll
      for (int k = 0; k < 16; ++k) ix[k] = csr_col[j + k];
      unsigned u[16];
#pragma unroll
      for (int k = 0; k < 16; ++k)
        u[k] = *(const unsigned*)(h + (size_t)ix[k] * DIM + ch);
      if (mode == 1) {
#pragma unroll
        for (int k = 0; k < 16; ++k) {
          a0 += fmaxf(bf2f((unsigned short)u[k]) * sc0 + sh0, 0.f);
          a1 += fmaxf(bf2f((unsigned short)(u[k] >> 16)) * sc1 + sh1, 0.f);
        }
      } else {
#pragma unroll
        for (int k = 0; k < 16; ++k) {
          a0 += bf2f((unsigned short)u[k]);
          a1 += bf2f((unsigned short)(u[k] >> 16));
        }
      }
    }
    if (j + 7 < end) {
      int ix[8];
#pragma unroll
      for (int k = 0; k < 8; ++k) ix[k] = csr_col[j + k];
      unsigned u[8];
#pragma unroll
      for (int k = 0; k < 8; ++k)
        u[k] = *(const unsigned*)(h + (size_t)ix[k] * DIM + ch);
#pragma unroll
      for (int k = 0; k < 8; ++k) {
        if (mode == 1) {
          a0 += fmaxf(bf2f((unsigned short)u[k]) * sc0 + sh0, 0.f);
          a1 += fmaxf(bf2f((unsigned short)(u[k] >> 16)) * sc1 + sh1, 0.f);
        } else {
          a0 += bf2f((unsigned short)u[k]);
          a1 += bf2f((unsigned short)(u[k] >> 16));
        }
      }
      j += 8;
    }
    if (j + 3 < end) {
      int ix[4];
#pragma unroll
      for (int k = 0; k < 4; ++k) ix[k] = csr_col[j + k];
      unsigned u[4];
#pragma unroll
      for (int k = 0; k < 4; ++k)
        u[k] = *(const unsigned*)(h + (size_t)ix[k] * DIM + ch);
#pragma unroll
      for (int k = 0; k < 4; ++k) {
        if (mode == 1) {
          a0 += fmaxf(bf2f((unsigned short)u[k]) * sc0 + sh0, 0.f);
          a1 += fmaxf(bf2f((unsigned short)(u[k] >> 16)) * sc1 + sh1, 0.f);
        } else {
          a0 += bf2f((unsigned short)u[k]);
          a1 += bf2f((unsigned short)(u[k] >> 16));
        }
      }
      j += 4;
    }
    for (; j < end; ++j) {
      unsigned u = *(const unsigned*)(h + (size_t)csr_col[j] * DIM + ch);
      if (mode == 1) {
        a0 += fmaxf(bf2f((unsigned short)u) * sc0 + sh0, 0.f);
        a1 += fmaxf(bf2f((unsigned short)(u >> 16)) * sc1 + sh1, 0.f);
      } else {
        a0 += bf2f((unsigned short)u);
        a1 += bf2f((unsigned short)(u >> 16));
      }
    }
  } else {
    const float* x = (const float*)src;
    int j = start;
    for (; j + 7 < end; j += 8) {
      int ix[8];
#pragma unroll
      for (int k = 0; k < 8; ++k) ix[k] = csr_col[j + k];
#pragma unroll
      for (int k = 0; k < 8; ++k) {
        float2 v = *(const float2*)(x + (size_t)ix[k] * DIM + ch);
        a0 += v.x; a1 += v.y;
      }
    }
    for (; j < end; ++j) {
      float2 v = *(const float2*)(x + (size_t)csr_col[j] * DIM + ch);
      a0 += v.x; a1 += v.y;
    }
  }
  unsigned o = (unsigned)f2bf(a0) | ((unsigned)f2bf(a1) << 16);
  *(unsigned*)(agg + (size_t)node * DIM + ch) = o;
}

// ================= MFMA GEMM (+BN transform in, +slotted stats out) ======
__global__ __launch_bounds__(256) void gemm_kernel(
    const void* __restrict__ Ap, const unsigned short* __restrict__ agg,
    const unsigned short* __restrict__ PWm, const float* __restrict__ bias,
    const float* __restrict__ stats_in, const float* __restrict__ gv,
    const float* __restrict__ bev, void* __restrict__ Cp,
    float* __restrict__ stats_out, const int* __restrict__ flagp,
    int a_ext, int add_agg, int out_ext) {
  __shared__ unsigned short As[64 * 136];
  __shared__ float red_s[256];
  __shared__ float red_q[256];
  __shared__ float ssl[256];
  const int tid = threadIdx.x;
  const int row0 = blockIdx.x * 64;
  const int bf = *flagp;
  const int has_tf = (stats_in != nullptr);

  if (has_tf) {
    if (tid < 128) {
      float s = 0.f, q = 0.f;
#pragma unroll
      for (int k = 0; k < NSLOT; ++k) {
        s += stats_in[k * 256 + tid];
        q += stats_in[k * 256 + 128 + tid];
      }
      const float invN = 1.0f / (float)N_NODES;
      float m = s * invN;
      float v = q * invN - m * m;
      float scv = gv[tid] * rsqrtf(v + BN_EPS);
      ssl[tid] = scv;
      ssl[128 + tid] = bev[tid] - m * scv;
    }
    __syncthreads();
  }

  for (int i = 0; i < 8; ++i) {
    int G = tid + i * 256;
    int lrow = G >> 5;
    int ch = (G & 31) * 4;
    int grow = row0 + lrow;
    float4 v = make_float4(0.f, 0.f, 0.f, 0.f);
    if (grow < N_NODES) {
      if (a_ext && !bf) {
        v = *(const float4*)((const float*)Ap + (size_t)grow * DIM + ch);
      } else {
        ushort4 u = *(const ushort4*)((const unsigned short*)Ap +
                                      (size_t)grow * DIM + ch);
        v = make_float4(bf2f(u.x), bf2f(u.y), bf2f(u.z), bf2f(u.w));
      }
      if (has_tf) {
        float4 sc = *(const float4*)&ssl[ch];
        float4 sh = *(const float4*)&ssl[128 + ch];
        v.x = fmaxf(v.x * sc.x + sh.x, 0.f);
        v.y = fmaxf(v.y * sc.y + sh.y, 0.f);
        v.z = fmaxf(v.z * sc.z + sh.z, 0.f);
        v.w = fmaxf(v.w * sc.w + sh.w, 0.f);
      }
      if (add_agg) {
        ushort4 au = *(const ushort4*)(agg + (size_t)grow * DIM + ch);
        v.x += bf2f(au.x); v.y += bf2f(au.y);
        v.z += bf2f(au.z); v.w += bf2f(au.w);
      }
    }
    ushort4 o;
    o.x = f2bf(v.x); o.y = f2bf(v.y); o.z = f2bf(v.z); o.w = f2bf(v.w);
    *(ushort4*)&As[lrow * 136 + ch] = o;
  }
  __syncthreads();

  const int wv = tid >> 6, lane = tid & 63;
  const int quad = lane >> 4, lo = lane & 15;
  accf4 acc[8];
#pragma unroll
  for (int nt = 0; nt < 8; ++nt) {
    acc[nt][0] = 0.f; acc[nt][1] = 0.f; acc[nt][2] = 0.f; acc[nt][3] = 0.f;
  }
#pragma unroll
  for (int kt = 0; kt < 4; ++kt) {
    bfrag8 a = *(const bfrag8*)&As[(wv * 16 + lo) * 136 + kt * 32 + quad * 8];
    const unsigned short* pw = PWm + kt * 4096 + lane * 8;
#pragma unroll
    for (int nt = 0; nt < 8; ++nt) {
      bfrag8 b = *(const bfrag8*)(pw + nt * 512);
      acc[nt] = __builtin_amdgcn_mfma_f32_16x16x32_bf16(a, b, acc[nt], 0, 0, 0);
    }
  }
  __syncthreads();

  if (out_ext && !bf) {
    float* Co = (float*)Cp;
#pragma unroll
    for (int nt = 0; nt < 8; ++nt) {
      float b = bias[nt * 16 + lo];
#pragma unroll
      for (int reg = 0; reg < 4; ++reg) {
        int grow = row0 + wv * 16 + quad * 4 + reg;
        if (grow < N_NODES)
          Co[(size_t)grow * DIM + nt * 16 + lo] = acc[nt][reg] + b;
      }
    }
  } else {
#pragma unroll
    for (int nt = 0; nt < 8; ++nt) {
      float b = bias[nt * 16 + lo];
#pragma unroll
      for (int reg = 0; reg < 4; ++reg) {
        As[(wv * 16 + quad * 4 + reg) * 136 + nt * 16 + lo] =
            f2bf(acc[nt][reg] + b);
      }
    }
    __syncthreads();
    unsigned short* Co = (unsigned short*)Cp;
    for (int i = 0; i < 8; ++i) {
      int G = tid + i * 256;
      int lrow = G >> 5, ch = (G & 31) * 4;
      int grow = row0 + lrow;
      if (grow < N_NODES)
        *(ushort4*)(Co + (size_t)grow * DIM + ch) =
            *(const ushort4*)&As[lrow * 136 + ch];
    }
    if (stats_out) {
      int c = tid & 127, rh = tid >> 7;
      int rmax = N_NODES - row0;
      if (rmax > 64) rmax = 64;
      int rend = rh * 32 + 32;
      if (rend > rmax) rend = rmax;
      float s = 0.f, q = 0.f;
      for (int r = rh * 32; r < rend; ++r) {
        float v = bf2f(As[r * 136 + c]);
        s += v; q += v * v;
      }
      red_s[tid] = s; red_q[tid] = q;
      __syncthreads();
      if (tid < 128) {
        float* so = stats_out + (size_t)(blockIdx.x & (NSLOT - 1)) * 256;
        atomicAdd(so + tid, red_s[tid] + red_s[tid + 128]);
        atomicAdd(so + 128 + tid, red_q[tid] + red_q[tid + 128]);
      }
    }
  }
}

extern "C" void kernel_launch(void* const* d_in, const int* in_sizes, int n_in,
                              void* d_out, int out_size, void* d_ws, size_t ws_size,
                              hipStream_t stream) {
  const void* x  = d_in[0];
  const int* row = (const int*)d_in[1];
  const int* col = (const int*)d_in[2];

  const size_t ND = (size_t)N_NODES * DIM;
  unsigned short* agg = (unsigned short*)d_ws;        // ND bf16
  unsigned short* hA  = agg + ND;                     // ND bf16
  unsigned short* hB  = hA + ND;                      // ND bf16
  unsigned short* PW  = hB + ND;                      // 4*16384 bf16
  float* PV    = (float*)(PW + 4 * 16384);            // 10*128 fp32
  float* ps2   = PV + 10 * DIM;                       // 3*NSLOT*256 fp32
  int*   flag  = (int*)(ps2 + 3 * NSLOT * 256);       // 1 (+pad)
  int*   deg   = flag + 4;                            // N
  int*   bcnt  = deg + N_NODES;                       // NBUCK (contiguous!)
  int*   offs  = bcnt + NBUCK;                        // N+1
  int*   csr_col = offs + N_NODES + 1;                // E
  uint2* ebuf  = (uint2*)((((size_t)(csr_col + N_EDGES)) + 15) & ~(size_t)15);

  float* S0 = ps2 + 0 * NSLOT * 256;
  float* S1 = ps2 + 1 * NSLOT * 256;
  float* S2 = ps2 + 2 * NSLOT * 256;

  float* c0_b1f = PV + 0 * DIM; float* c0_gf  = PV + 1 * DIM;
  float* c0_bef = PV + 2 * DIM; float* c0_b2f = PV + 3 * DIM;
  float* bn0_gf = PV + 4 * DIM; float* bn0_bef= PV + 5 * DIM;
  float* c1_b1f = PV + 6 * DIM; float* c1_gf  = PV + 7 * DIM;
  float* c1_bef = PV + 8 * DIM; float* c1_b2f = PV + 9 * DIM;

  const int grow_grid = (N_NODES + 3) / 4;  // 12500

  PPtrs pp;
  pp.xs = x;
  pp.w[0] = d_in[3];  pp.w[1] = d_in[7];  pp.w[2] = d_in[11]; pp.w[3] = d_in[15];
  pp.v[0] = d_in[4];  pp.v[1] = d_in[5];  pp.v[2] = d_in[6];  pp.v[3] = d_in[8];
  pp.v[4] = d_in[9];  pp.v[5] = d_in[10]; pp.v[6] = d_in[12]; pp.v[7] = d_in[13];
  pp.v[8] = d_in[14]; pp.v[9] = d_in[16];

  // prep: detect + weights + vectors + flag + zero(ps2, deg, bcnt)
  prep_kernel<<<40, 256, 0, stream>>>(pp, PW, PV, flag, ps2, deg);

  // CSR build (2 dispatches)
  binA_kernel<<<BINA_BLOCKS, 256, 0, stream>>>(row, col, deg, bcnt, ebuf);
  binB_kernel<<<NBUCK, 256, 0, stream>>>(deg, bcnt, ebuf, csr_col, offs);

  // ---- conv0 ----
  gather_row_kernel<<<grow_grid, 256, 0, stream>>>(
      x, offs, csr_col, nullptr, nullptr, nullptr, agg, flag, 0);
  gemm_kernel<<<GEMM_GRID, 256, 0, stream>>>(
      x, agg, PW + 0 * 16384, c0_b1f, nullptr, nullptr, nullptr,
      hA, S0, flag, 1, 1, 0);
  gemm_kernel<<<GEMM_GRID, 256, 0, stream>>>(
      hA, nullptr, PW + 1 * 16384, c0_b2f, S0, c0_gf, c0_bef,
      hB, S1, flag, 0, 0, 0);

  // ---- conv1 ----
  gather_row_kernel<<<grow_grid, 256, 0, stream>>>(
      hB, offs, csr_col, S1, bn0_gf, bn0_bef, agg, flag, 1);
  gemm_kernel<<<GEMM_GRID, 256, 0, stream>>>(
      hB, agg, PW + 2 * 16384, c1_b1f, S1, bn0_gf, bn0_bef,
      hA, S2, flag, 0, 1, 0);
  gemm_kernel<<<GEMM_GRID, 256, 0, stream>>>(
      hA, nullptr, PW + 3 * 16384, c1_b2f, S2, c1_gf, c1_bef,
      d_out, nullptr, flag, 0, 0, 1);
}

// Round 4
// 330.261 us; speedup vs baseline: 2.5546x; 1.0107x over previous
//
#include <hip/hip_runtime.h>

// GIN 2-layer forward, MI355X (gfx950). Round 15: un-serialize gather loads.
//  Round-3 analysis: gather VGPR_Count=32 forced the compiler to split the
//  unroll-16 load batch into tiny load->wait->consume groups (~1 outstanding
//  256B load/wave). Little's law: 256CU x 21 waves x 256B/900cy = 3.45TB/s
//  == measured. The "wall" was register-starved MLP, not bandwidth.
//  Fix: __launch_bounds__(256,4) on gather (allows ~128 VGPR) so all 16
//  feature loads stay in flight. Everything else identical to round 14.

#define N_NODES 50000
#define N_EDGES 800000
#define DIM 128
#define BN_EPS 1e-5f
#define GEMM_GRID 782           // ceil(N_NODES/64)
#define NBUCK 256
#define NPB 196                 // nodes per bucket
#define BCAP 4096               // max edges per bucket
#define BINA_BLOCKS 128
#define EPB (N_EDGES / BINA_BLOCKS)
#define CBLK 12500              // col-block width (kept from r13, perf-neutral)
#define NSLOT 16                // stats atomic slots

using bfrag8 = __attribute__((ext_vector_type(8))) short;
using accf4  = __attribute__((ext_vector_type(4))) float;

__device__ __forceinline__ float bf2f(unsigned short u) {
  union { unsigned u32; float f; } c;
  c.u32 = ((unsigned)u) << 16;
  return c.f;
}
__device__ __forceinline__ unsigned short f2bf(float f) {
  union { float f; unsigned u32; } c;
  c.f = f;
  unsigned u = c.u32;
  return (unsigned short)((u + 0x7fffu + ((u >> 16) & 1u)) >> 16);  // RNE
}

// ---- prep: detect dtype, pack weights, convert vectors, zero scratch ----
struct PPtrs { const void* xs; const void* w[4]; const void* v[10]; };

__global__ __launch_bounds__(256) void prep_kernel(
    PPtrs pp, unsigned short* __restrict__ PW, float* __restrict__ PV,
    int* __restrict__ flag, float* __restrict__ ps2, int* __restrict__ deg) {
  __shared__ int oks[64];
  __shared__ int bfs;
  int t = threadIdx.x;
  // per-block dtype self-detection (64 samples of x)
  if (t < 64) {
    unsigned short u = ((const unsigned short*)pp.xs)[t * 2];
    int e = (u >> 7) & 0xFF;
    oks[t] = ((e >= 96 && e <= 134) || ((u & 0x7FFFu) == 0)) ? 1 : 0;
  }
  __syncthreads();
  if (t == 0) {
    int c = 0;
    for (int i = 0; i < 64; ++i) c += oks[i];
    bfs = (c >= 56) ? 1 : 0;
  }
  __syncthreads();
  int bf = bfs;
  int b = blockIdx.x;

  if (b < 4) {
    // pack weight matrix b into MFMA B-frag layout
    const void* src = pp.w[b];
    unsigned short* dst = PW + (size_t)b * 16384;
    for (int f = t; f < 2048; f += 256) {
      int kt = f >> 9, nt = (f >> 6) & 7, lane = f & 63;
      int kbase = kt * 32 + (lane >> 4) * 8;
      int n = nt * 16 + (lane & 15);
      unsigned short tmp[8];
      for (int j = 0; j < 8; ++j) {
        int idx = (kbase + j) * DIM + n;
        if (bf) tmp[j] = ((const unsigned short*)src)[idx];
        else    tmp[j] = f2bf(((const float*)src)[idx]);
      }
      for (int j = 0; j < 8; ++j) dst[f * 8 + j] = tmp[j];
    }
  } else if (b == 4) {
    // vectors, flag, zero stats slots
    for (int j = t; j < 10 * DIM; j += 256) {
      int vec = j >> 7, idx = j & 127;
      float v;
      if (bf) v = bf2f(((const unsigned short*)pp.v[vec])[idx]);
      else    v = ((const float*)pp.v[vec])[idx];
      PV[j] = v;
    }
    if (t == 0) *flag = bf;
    for (int j = t; j < 3 * NSLOT * 256; j += 256) ps2[j] = 0.f;
  } else {
    // blocks 5..39 zero deg[N] + bcnt[NBUCK] (contiguous)
    const int total = N_NODES + NBUCK;
    for (int i = (b - 5) * 256 + t; i < total; i += 35 * 256) deg[i] = 0;
  }
}

// ================= CSR build =================
__global__ __launch_bounds__(256) void binA_kernel(
    const int* __restrict__ row, const int* __restrict__ col,
    int* __restrict__ deg, int* __restrict__ bcnt, uint2* __restrict__ ebuf) {
  __shared__ int hist[NBUCK];
  __shared__ int base[NBUCK];
  int t = threadIdx.x;
  int e0 = blockIdx.x * EPB;
  hist[t] = 0;
  __syncthreads();
  for (int i = t; i < EPB; i += 256) {
    int r = row[e0 + i];
    atomicAdd(&deg[r], 1);
    atomicAdd(&hist[r / NPB], 1);
  }
  __syncthreads();
  base[t] = atomicAdd(&bcnt[t], hist[t]);
  hist[t] = 0;
  __syncthreads();
  for (int i = t; i < EPB; i += 256) {
    int r = row[e0 + i];
    int c = col[e0 + i];
    int b = r / NPB;
    int rank = atomicAdd(&hist[b], 1);
    ebuf[(size_t)b * BCAP + base[b] + rank] = make_uint2((unsigned)r, (unsigned)c);
  }
}

// binB: per-block redundant scan of bcnt -> segbase; local degree scan ->
// offs; col-block-ordered scatter into csr_col.
__global__ __launch_bounds__(256) void binB_kernel(
    const int* __restrict__ deg, const int* __restrict__ bcnt,
    const uint2* __restrict__ ebuf, int* __restrict__ csr_col,
    int* __restrict__ offs) {
  __shared__ int sc[256];        // bcnt inclusive scan
  __shared__ int dg[256];        // local degree inclusive scan
  __shared__ int cur4[NPB * 4];
  __shared__ int seg[BCAP];
  int b = blockIdx.x;
  int t = threadIdx.x;

  sc[t] = bcnt[t];
  __syncthreads();
  for (int d = 1; d < 256; d <<= 1) {
    int v = (t >= d) ? sc[t - d] : 0;
    __syncthreads();
    sc[t] += v;
    __syncthreads();
  }
  int segbase = (b == 0) ? 0 : sc[b - 1];

  int nb = b * NPB;
  int nend = nb + NPB;
  if (nend > N_NODES) nend = N_NODES;
  int nn = nend - nb;

  int myd = (t < nn) ? deg[nb + t] : 0;
  dg[t] = myd;
  __syncthreads();
  for (int d = 1; d < 256; d <<= 1) {
    int v = (t >= d) ? dg[t - d] : 0;
    __syncthreads();
    dg[t] += v;
    __syncthreads();
  }
  int excl = dg[t] - myd;       // local exclusive prefix (valid for t < nn)
  if (t < nn) offs[nb + t] = segbase + excl;
  if (b == NBUCK - 1 && t == 0) offs[N_NODES] = N_EDGES;

  int cnt = bcnt[b];
  const uint2* eb = ebuf + (size_t)b * BCAP;
  for (int i = t; i < nn * 4; i += 256) cur4[i] = 0;
  __syncthreads();
  // count per (node, col-block)
  for (int i = t; i < cnt; i += 256) {
    uint2 e = eb[i];
    int blk = (int)e.y / CBLK;
    atomicAdd(&cur4[(e.x - (unsigned)nb) * 4 + blk], 1);
  }
  __syncthreads();
  // per-node 4-way prefix -> local running starts (t<nn: nn<=196<256)
  if (t < nn) {
    int run = excl;
    int c0 = cur4[t * 4 + 0], c1 = cur4[t * 4 + 1];
    int c2 = cur4[t * 4 + 2];
    cur4[t * 4 + 0] = run;
    cur4[t * 4 + 1] = run + c0;
    cur4[t * 4 + 2] = run + c0 + c1;
    cur4[t * 4 + 3] = run + c0 + c1 + c2;
  }
  __syncthreads();
  // scatter in (node, blk) order
  for (int i = t; i < cnt; i += 256) {
    uint2 e = eb[i];
    int blk = (int)e.y / CBLK;
    int slot = atomicAdd(&cur4[(e.x - (unsigned)nb) * 4 + blk], 1);
    seg[slot] = (int)e.y;
  }
  __syncthreads();
  for (int i = t; i < cnt; i += 256)
    csr_col[segbase + i] = seg[i];
}

// ================= full-row gather, unroll-16, MLP-enabled =================
// Wave = 1 node; lane owns 2 channels (4B) => one wave instruction reads the
// whole 256B feature row of one neighbor. __launch_bounds__(256,4) relaxes
// the VGPR budget (was 32 -> serialized loads); all 16 loads stay in flight.
// mode 0: plain sum; mode 1: relu(v*sc+sh) from slotted stats + g/be.
__global__ __launch_bounds__(256, 4) void gather_row_kernel(
    const void* __restrict__ src, const int* __restrict__ offs,
    const int* __restrict__ csr_col, const float* __restrict__ stats_in,
    const float* __restrict__ gv, const float* __restrict__ bev,
    unsigned short* __restrict__ agg, const int* __restrict__ flagp,
    int mode) {
  __shared__ float ssl[256];
  int tid = threadIdx.x;
  if (mode == 1) {
    if (tid < 128) {
      float s = 0.f, q = 0.f;
#pragma unroll
      for (int k = 0; k < NSLOT; ++k) {
        s += stats_in[k * 256 + tid];
        q += stats_in[k * 256 + 128 + tid];
      }
      const float invN = 1.0f / (float)N_NODES;
      float m = s * invN;
      float v = q * invN - m * m;
      float scv = gv[tid] * rsqrtf(v + BN_EPS);
      ssl[tid] = scv;
      ssl[128 + tid] = bev[tid] - m * scv;
    }
    __syncthreads();
  }

  int node = blockIdx.x * 4 + (tid >> 6);
  if (node >= N_NODES) return;
  int lane = tid & 63;
  int ch = lane * 2;
  int start = offs[node], end = offs[node + 1];
  float a0 = 0.f, a1 = 0.f;
  int bf = *flagp;
  float sc0 = 0.f, sc1 = 0.f, sh0 = 0.f, sh1 = 0.f;
  if (mode == 1) {
    sc0 = ssl[ch]; sc1 = ssl[ch + 1];
    sh0 = ssl[128 + ch]; sh1 = ssl[128 + ch + 1];
  }

  if (mode == 1 || bf) {
    const unsigned short* h = (const unsigned short*)src;
    int j = start;
    for (; j + 15 < end; j += 16) {
      int ix[16];
#pragma unroll
      for (int k = 0; k < 16; ++k) ix[k] = csr_col[j + k];
      unsigned u[16];
#pragma unroll
      for (int k = 0; k < 16; ++k)
        u[k] = *(const unsigned*)(h + (size_t)ix[k] * DIM + ch);
      if (mode == 1) {
#pragma unroll
        for (int k = 0; k < 16; ++k) {
          a0 += fmaxf(bf2f((unsigned short)u[k]) * sc0 + sh0, 0.f);
          a1 += fmaxf(bf2f((unsigned short)(u[k] >> 16)) * sc1 + sh1, 0.f);
        }
      } else {
#pragma unroll
        for (int k = 0; k < 16; ++k) {
          a0 += bf2f((unsigned short)u[k]);
          a1 += bf2f((unsigned short)(u[k] >> 16));
        }
      }
    }
    if (j + 7 < end) {
      int ix[8];
#pragma unroll
      for (int k = 0; k < 8; ++k) ix[k] = csr_col[j + k];
      unsigned u[8];
#pragma unroll
      for (int k = 0; k < 8; ++k)
        u[k] = *(const unsigned*)(h + (size_t)ix[k] * DIM + ch);
#pragma unroll
      for (int k = 0; k < 8; ++k) {
        if (mode == 1) {
          a0 += fmaxf(bf2f((unsigned short)u[k]) * sc0 + sh0, 0.f);
          a1 += fmaxf(bf2f((unsigned short)(u[k] >> 16)) * sc1 + sh1, 0.f);
        } else {
          a0 += bf2f((unsigned short)u[k]);
          a1 += bf2f((unsigned short)(u[k] >> 16));
        }
      }
      j += 8;
    }
    if (j + 3 < end) {
      int ix[4];
#pragma unroll
      for (int k = 0; k < 4; ++k) ix[k] = csr_col[j + k];
      unsigned u[4];
#pragma unroll
      for (int k = 0; k < 4; ++k)
        u[k] = *(const unsigned*)(h + (size_t)ix[k] * DIM + ch);
#pragma unroll
      for (int k = 0; k < 4; ++k) {
        if (mode == 1) {
          a0 += fmaxf(bf2f((unsigned short)u[k]) * sc0 + sh0, 0.f);
          a1 += fmaxf(bf2f((unsigned short)(u[k] >> 16)) * sc1 + sh1, 0.f);
        } else {
          a0 += bf2f((unsigned short)u[k]);
          a1 += bf2f((unsigned short)(u[k] >> 16));
        }
      }
      j += 4;
    }
    for (; j < end; ++j) {
      unsigned u = *(const unsigned*)(h + (size_t)csr_col[j] * DIM + ch);
      if (mode == 1) {
        a0 += fmaxf(bf2f((unsigned short)u) * sc0 + sh0, 0.f);
        a1 += fmaxf(bf2f((unsigned short)(u >> 16)) * sc1 + sh1, 0.f);
      } else {
        a0 += bf2f((unsigned short)u);
        a1 += bf2f((unsigned short)(u >> 16));
      }
    }
  } else {
    const float* x = (const float*)src;
    int j = start;
    for (; j + 7 < end; j += 8) {
      int ix[8];
#pragma unroll
      for (int k = 0; k < 8; ++k) ix[k] = csr_col[j + k];
#pragma unroll
      for (int k = 0; k < 8; ++k) {
        float2 v = *(const float2*)(x + (size_t)ix[k] * DIM + ch);
        a0 += v.x; a1 += v.y;
      }
    }
    for (; j < end; ++j) {
      float2 v = *(const float2*)(x + (size_t)csr_col[j] * DIM + ch);
      a0 += v.x; a1 += v.y;
    }
  }
  unsigned o = (unsigned)f2bf(a0) | ((unsigned)f2bf(a1) << 16);
  *(unsigned*)(agg + (size_t)node * DIM + ch) = o;
}

// ================= MFMA GEMM (+BN transform in, +slotted stats out) ======
__global__ __launch_bounds__(256) void gemm_kernel(
    const void* __restrict__ Ap, const unsigned short* __restrict__ agg,
    const unsigned short* __restrict__ PWm, const float* __restrict__ bias,
    const float* __restrict__ stats_in, const float* __restrict__ gv,
    const float* __restrict__ bev, void* __restrict__ Cp,
    float* __restrict__ stats_out, const int* __restrict__ flagp,
    int a_ext, int add_agg, int out_ext) {
  __shared__ unsigned short As[64 * 136];
  __shared__ float red_s[256];
  __shared__ float red_q[256];
  __shared__ float ssl[256];
  const int tid = threadIdx.x;
  const int row0 = blockIdx.x * 64;
  const int bf = *flagp;
  const int has_tf = (stats_in != nullptr);

  if (has_tf) {
    if (tid < 128) {
      float s = 0.f, q = 0.f;
#pragma unroll
      for (int k = 0; k < NSLOT; ++k) {
        s += stats_in[k * 256 + tid];
        q += stats_in[k * 256 + 128 + tid];
      }
      const float invN = 1.0f / (float)N_NODES;
      float m = s * invN;
      float v = q * invN - m * m;
      float scv = gv[tid] * rsqrtf(v + BN_EPS);
      ssl[tid] = scv;
      ssl[128 + tid] = bev[tid] - m * scv;
    }
    __syncthreads();
  }

  for (int i = 0; i < 8; ++i) {
    int G = tid + i * 256;
    int lrow = G >> 5;
    int ch = (G & 31) * 4;
    int grow = row0 + lrow;
    float4 v = make_float4(0.f, 0.f, 0.f, 0.f);
    if (grow < N_NODES) {
      if (a_ext && !bf) {
        v = *(const float4*)((const float*)Ap + (size_t)grow * DIM + ch);
      } else {
        ushort4 u = *(const ushort4*)((const unsigned short*)Ap +
                                      (size_t)grow * DIM + ch);
        v = make_float4(bf2f(u.x), bf2f(u.y), bf2f(u.z), bf2f(u.w));
      }
      if (has_tf) {
        float4 sc = *(const float4*)&ssl[ch];
        float4 sh = *(const float4*)&ssl[128 + ch];
        v.x = fmaxf(v.x * sc.x + sh.x, 0.f);
        v.y = fmaxf(v.y * sc.y + sh.y, 0.f);
        v.z = fmaxf(v.z * sc.z + sh.z, 0.f);
        v.w = fmaxf(v.w * sc.w + sh.w, 0.f);
      }
      if (add_agg) {
        ushort4 au = *(const ushort4*)(agg + (size_t)grow * DIM + ch);
        v.x += bf2f(au.x); v.y += bf2f(au.y);
        v.z += bf2f(au.z); v.w += bf2f(au.w);
      }
    }
    ushort4 o;
    o.x = f2bf(v.x); o.y = f2bf(v.y); o.z = f2bf(v.z); o.w = f2bf(v.w);
    *(ushort4*)&As[lrow * 136 + ch] = o;
  }
  __syncthreads();

  const int wv = tid >> 6, lane = tid & 63;
  const int quad = lane >> 4, lo = lane & 15;
  accf4 acc[8];
#pragma unroll
  for (int nt = 0; nt < 8; ++nt) {
    acc[nt][0] = 0.f; acc[nt][1] = 0.f; acc[nt][2] = 0.f; acc[nt][3] = 0.f;
  }
#pragma unroll
  for (int kt = 0; kt < 4; ++kt) {
    bfrag8 a = *(const bfrag8*)&As[(wv * 16 + lo) * 136 + kt * 32 + quad * 8];
    const unsigned short* pw = PWm + kt * 4096 + lane * 8;
#pragma unroll
    for (int nt = 0; nt < 8; ++nt) {
      bfrag8 b = *(const bfrag8*)(pw + nt * 512);
      acc[nt] = __builtin_amdgcn_mfma_f32_16x16x32_bf16(a, b, acc[nt], 0, 0, 0);
    }
  }
  __syncthreads();

  if (out_ext && !bf) {
    float* Co = (float*)Cp;
#pragma unroll
    for (int nt = 0; nt < 8; ++nt) {
      float b = bias[nt * 16 + lo];
#pragma unroll
      for (int reg = 0; reg < 4; ++reg) {
        int grow = row0 + wv * 16 + quad * 4 + reg;
        if (grow < N_NODES)
          Co[(size_t)grow * DIM + nt * 16 + lo] = acc[nt][reg] + b;
      }
    }
  } else {
#pragma unroll
    for (int nt = 0; nt < 8; ++nt) {
      float b = bias[nt * 16 + lo];
#pragma unroll
      for (int reg = 0; reg < 4; ++reg) {
        As[(wv * 16 + quad * 4 + reg) * 136 + nt * 16 + lo] =
            f2bf(acc[nt][reg] + b);
      }
    }
    __syncthreads();
    unsigned short* Co = (unsigned short*)Cp;
    for (int i = 0; i < 8; ++i) {
      int G = tid + i * 256;
      int lrow = G >> 5, ch = (G & 31) * 4;
      int grow = row0 + lrow;
      if (grow < N_NODES)
        *(ushort4*)(Co + (size_t)grow * DIM + ch) =
            *(const ushort4*)&As[lrow * 136 + ch];
    }
    if (stats_out) {
      int c = tid & 127, rh = tid >> 7;
      int rmax = N_NODES - row0;
      if (rmax > 64) rmax = 64;
      int rend = rh * 32 + 32;
      if (rend > rmax) rend = rmax;
      float s = 0.f, q = 0.f;
      for (int r = rh * 32; r < rend; ++r) {
        float v = bf2f(As[r * 136 + c]);
        s += v; q += v * v;
      }
      red_s[tid] = s; red_q[tid] = q;
      __syncthreads();
      if (tid < 128) {
        float* so = stats_out + (size_t)(blockIdx.x & (NSLOT - 1)) * 256;
        atomicAdd(so + tid, red_s[tid] + red_s[tid + 128]);
        atomicAdd(so + 128 + tid, red_q[tid] + red_q[tid + 128]);
      }
    }
  }
}

extern "C" void kernel_launch(void* const* d_in, const int* in_sizes, int n_in,
                              void* d_out, int out_size, void* d_ws, size_t ws_size,
                              hipStream_t stream) {
  const void* x  = d_in[0];
  const int* row = (const int*)d_in[1];
  const int* col = (const int*)d_in[2];

  const size_t ND = (size_t)N_NODES * DIM;
  unsigned short* agg = (unsigned short*)d_ws;        // ND bf16
  unsigned short* hA  = agg + ND;                     // ND bf16
  unsigned short* hB  = hA + ND;                      // ND bf16
  unsigned short* PW  = hB + ND;                      // 4*16384 bf16
  float* PV    = (float*)(PW + 4 * 16384);            // 10*128 fp32
  float* ps2   = PV + 10 * DIM;                       // 3*NSLOT*256 fp32
  int*   flag  = (int*)(ps2 + 3 * NSLOT * 256);       // 1 (+pad)
  int*   deg   = flag + 4;                            // N
  int*   bcnt  = deg + N_NODES;                       // NBUCK (contiguous!)
  int*   offs  = bcnt + NBUCK;                        // N+1
  int*   csr_col = offs + N_NODES + 1;                // E
  uint2* ebuf  = (uint2*)((((size_t)(csr_col + N_EDGES)) + 15) & ~(size_t)15);

  float* S0 = ps2 + 0 * NSLOT * 256;
  float* S1 = ps2 + 1 * NSLOT * 256;
  float* S2 = ps2 + 2 * NSLOT * 256;

  float* c0_b1f = PV + 0 * DIM; float* c0_gf  = PV + 1 * DIM;
  float* c0_bef = PV + 2 * DIM; float* c0_b2f = PV + 3 * DIM;
  float* bn0_gf = PV + 4 * DIM; float* bn0_bef= PV + 5 * DIM;
  float* c1_b1f = PV + 6 * DIM; float* c1_gf  = PV + 7 * DIM;
  float* c1_bef = PV + 8 * DIM; float* c1_b2f = PV + 9 * DIM;

  const int grow_grid = (N_NODES + 3) / 4;  // 12500

  PPtrs pp;
  pp.xs = x;
  pp.w[0] = d_in[3];  pp.w[1] = d_in[7];  pp.w[2] = d_in[11]; pp.w[3] = d_in[15];
  pp.v[0] = d_in[4];  pp.v[1] = d_in[5];  pp.v[2] = d_in[6];  pp.v[3] = d_in[8];
  pp.v[4] = d_in[9];  pp.v[5] = d_in[10]; pp.v[6] = d_in[12]; pp.v[7] = d_in[13];
  pp.v[8] = d_in[14]; pp.v[9] = d_in[16];

  // prep: detect + weights + vectors + flag + zero(ps2, deg, bcnt)
  prep_kernel<<<40, 256, 0, stream>>>(pp, PW, PV, flag, ps2, deg);

  // CSR build (2 dispatches)
  binA_kernel<<<BINA_BLOCKS, 256, 0, stream>>>(row, col, deg, bcnt, ebuf);
  binB_kernel<<<NBUCK, 256, 0, stream>>>(deg, bcnt, ebuf, csr_col, offs);

  // ---- conv0 ----
  gather_row_kernel<<<grow_grid, 256, 0, stream>>>(
      x, offs, csr_col, nullptr, nullptr, nullptr, agg, flag, 0);
  gemm_kernel<<<GEMM_GRID, 256, 0, stream>>>(
      x, agg, PW + 0 * 16384, c0_b1f, nullptr, nullptr, nullptr,
      hA, S0, flag, 1, 1, 0);
  gemm_kernel<<<GEMM_GRID, 256, 0, stream>>>(
      hA, nullptr, PW + 1 * 16384, c0_b2f, S0, c0_gf, c0_bef,
      hB, S1, flag, 0, 0, 0);

  // ---- conv1 ----
  gather_row_kernel<<<grow_grid, 256, 0, stream>>>(
      hB, offs, csr_col, S1, bn0_gf, bn0_bef, agg, flag, 1);
  gemm_kernel<<<GEMM_GRID, 256, 0, stream>>>(
      hB, agg, PW + 2 * 16384, c1_b1f, S1, bn0_gf, bn0_bef,
      hA, S2, flag, 0, 1, 0);
  gemm_kernel<<<GEMM_GRID, 256, 0, stream>>>(
      hA, nullptr, PW + 3 * 16384, c1_b2f, S2, c1_gf, c1_bef,
      d_out, nullptr, flag, 0, 0, 1);
}